// Round 2
// baseline (4733.955 us; speedup 1.0000x reference)
//
#include <hip/hip_runtime.h>

// ---------------- constants ----------------
constexpr int NT = 64;     // timesteps
constexpr int NB = 64;     // batch
constexpr int NV = 32000;  // vocab
constexpr int NE = 512;    // embed
constexpr int NH = 512;    // hidden
constexpr int NWG = 96;    // 64 A-wgs + 32 B-wgs, all resident (1 wg/CU, LDS-bound)

constexpr size_t SZ_OW  = (size_t)NV * NE;          // 16,384,000
constexpr size_t SZ_XE  = (size_t)NT * NB * NE;     // 2,097,152
constexpr size_t SZ_H   = (size_t)NB * NH;          // 32,768
constexpr size_t LOGITS = (size_t)NT * NB * NV;     // 131,072,000

typedef float f32x4 __attribute__((ext_vector_type(4)));
typedef short bf16x8 __attribute__((ext_vector_type(8)));
typedef short s16x4 __attribute__((ext_vector_type(4)));
typedef _Float16 f16x8 __attribute__((ext_vector_type(8)));

// ---------------- helpers ----------------
__device__ __forceinline__ unsigned short f2bf(float x) {
  unsigned u = __float_as_uint(x);
  u += 0x7FFFu + ((u >> 16) & 1u);            // RNE
  return (unsigned short)(u >> 16);
}
__device__ __forceinline__ float bf2f(unsigned short s) {
  return __uint_as_float(((unsigned)s) << 16);
}
__device__ __forceinline__ void split2(float v, short* hi, short* lo) {
  unsigned short h = f2bf(v);
  *hi = (short)h;
  *lo = (short)f2bf(v - bf2f(h));
}
__device__ __forceinline__ f32x4 mma_bf16(bf16x8 a, bf16x8 b, f32x4 c) {
  return __builtin_amdgcn_mfma_f32_16x16x32_bf16(a, b, c, 0, 0, 0);
}
__device__ __forceinline__ f32x4 mma_f16(f16x8 a, f16x8 b, f32x4 c) {
  return __builtin_amdgcn_mfma_f32_16x16x32_f16(a, b, c, 0, 0, 0);
}

// device-scope barrier among all resident workgroups (monotonic counter).
// tid0-only polling: its agent-acquire invalidates CU L1 (+XCD L2) once per round.
__device__ __forceinline__ void gbar(unsigned* bar, unsigned target) {
  __threadfence();           // release this wg's writes
  __syncthreads();
  if (threadIdx.x == 0) {
    __hip_atomic_fetch_add(bar, 1u, __ATOMIC_RELEASE, __HIP_MEMORY_SCOPE_AGENT);
    while (__hip_atomic_load(bar, __ATOMIC_ACQUIRE, __HIP_MEMORY_SCOPE_AGENT) < target)
      __builtin_amdgcn_s_sleep(2);
  }
  __syncthreads();
}

// ---------------- prep: OW cast, embed split, init state ----------------
__global__ void k_prep(
    const float* __restrict__ outw, const int* __restrict__ toks,
    const float* __restrict__ emb, const float* __restrict__ hid,
    _Float16* OWf, short* XeHi, short* XeLo,
    short* X1Hi, short* X1Lo, short* h0Hi, short* h0Lo) {
  const size_t stride = (size_t)gridDim.x * blockDim.x;
  const size_t N1 = SZ_OW, N2 = N1 + SZ_XE, N3 = N2 + SZ_H, N4 = N3 + SZ_H;
  for (size_t x = (size_t)blockIdx.x * blockDim.x + threadIdx.x; x < N4; x += stride) {
    if (x < N1) {
      OWf[x] = (_Float16)outw[x];
    } else if (x < N2) {
      size_t p = x - N1;
      size_t r = p >> 9, c = p & 511u;
      int tok = toks[r];
      float v = emb[(size_t)tok * 512 + c];
      short hi, lo; split2(v, &hi, &lo);
      XeHi[p] = hi; XeLo[p] = lo;
    } else if (x < N3) {
      size_t p = x - N2;
      short hi, lo; split2(hid[p], &hi, &lo);
      h0Hi[p] = hi; h0Lo[p] = lo;
    } else {
      size_t p = x - N3;
      short hi, lo; split2(hid[SZ_H + p], &hi, &lo);
      X1Hi[p] = hi; X1Lo[p] = lo;
    }
  }
}

// ---------------- recurrence MMA core ----------------
// Wave covers k in [kkGlob0, kkGlob0+256) and 2 row-tiles (32 batch rows).
// A = activation concat [aLo(0..511)|aHi(512..1023)], hi/lo split arrays [64][512].
// B = wg's 32-col weight slice in LDS (hi/lo), XOR-swizzled.
__device__ __forceinline__ void mma_block(
    const short* __restrict__ pAH, const short* __restrict__ pAL,
    int kloc0, int kkGlob0,
    const short* lsHi_, const short* lsLo_,
    f32x4 (&accH)[2][2], f32x4 (&accL)[2][2],
    int l15, int lq, int rhalf) {
  const int r0 = (rhalf * 2) * 16 + l15;
  const int r1 = (rhalf * 2 + 1) * 16 + l15;
#pragma unroll 4
  for (int i = 0; i < 8; ++i) {
    const int kk = kkGlob0 + i * 32 + lq * 8;   // global k (LDS index)
    const int ka = kloc0 + i * 32 + lq * 8;     // local k within act array
    const int e0 = (l15 * 1024 + kk) ^ ((l15 & 7) << 3);
    const int e1 = ((16 + l15) * 1024 + kk) ^ ((l15 & 7) << 3);
    bf16x8 bh0 = *(const bf16x8*)&lsHi_[e0];
    bf16x8 bl0 = *(const bf16x8*)&lsLo_[e0];
    bf16x8 bh1 = *(const bf16x8*)&lsHi_[e1];
    bf16x8 bl1 = *(const bf16x8*)&lsLo_[e1];
    bf16x8 a0h = *(const bf16x8*)&pAH[r0 * 512 + ka];
    bf16x8 a0l = *(const bf16x8*)&pAL[r0 * 512 + ka];
    bf16x8 a1h = *(const bf16x8*)&pAH[r1 * 512 + ka];
    bf16x8 a1l = *(const bf16x8*)&pAL[r1 * 512 + ka];
    accH[0][0] = mma_bf16(a0h, bh0, accH[0][0]);
    accH[0][1] = mma_bf16(a1h, bh0, accH[0][1]);
    accH[1][0] = mma_bf16(a0h, bh1, accH[1][0]);
    accH[1][1] = mma_bf16(a1h, bh1, accH[1][1]);
    accL[0][0] = mma_bf16(a0l, bh0, accL[0][0]);
    accL[0][1] = mma_bf16(a1l, bh0, accL[0][1]);
    accL[1][0] = mma_bf16(a0l, bh1, accL[1][0]);
    accL[1][1] = mma_bf16(a1l, bh1, accL[1][1]);
    accL[0][0] = mma_bf16(a0h, bl0, accL[0][0]);
    accL[0][1] = mma_bf16(a1h, bl0, accL[0][1]);
    accL[1][0] = mma_bf16(a0h, bl1, accL[1][0]);
    accL[1][1] = mma_bf16(a1h, bl1, accL[1][1]);
  }
}

// Full-wg phase: MMA + cross-wave k-reduction. After return, waves 0,1 hold
// final sums in acc (wave w owns row-tiles 2w, 2w+1 via rti; cols jc+ct*16+l15).
__device__ __forceinline__ void phase_mma_reduce(
    const short* aLoH, const short* aLoL,
    const short* aHiH, const short* aHiL,
    const short* lsHi_, const short* lsLo_, float* lsRed_,
    f32x4 (&acc)[2][2], int wave, int l15, int lq) {
  const int khalf = wave >> 1, rhalf = wave & 1;
  f32x4 accH[2][2] = {}, accL[2][2] = {};
  const short* pAH = (khalf < 2) ? aLoH : aHiH;
  const short* pAL = (khalf < 2) ? aLoL : aHiL;
  mma_block(pAH, pAL, (khalf & 1) * 256, khalf * 256, lsHi_, lsLo_,
            accH, accL, l15, lq, rhalf);
#pragma unroll
  for (int ct = 0; ct < 2; ++ct)
#pragma unroll
    for (int rti = 0; rti < 2; ++rti) acc[ct][rti] = accH[ct][rti] + accL[ct][rti];
  const int pos = l15 * 16 + lq * 4;        // transposed tile: col-major, f32x4 contiguous
  if (wave >= 2) {
#pragma unroll
    for (int ct = 0; ct < 2; ++ct)
#pragma unroll
      for (int rti = 0; rti < 2; ++rti)
        *(f32x4*)&lsRed_[(((wave - 2) * 2 + ct) * 2 + rti) * 256 + pos] = acc[ct][rti];
  }
  __syncthreads();
  if (wave < 2) {
#pragma unroll
    for (int s = 0; s < 3; ++s) {
      const int swi = rhalf + 2 * s;        // partials from waves {rhalf+2, +4, +6}
#pragma unroll
      for (int ct = 0; ct < 2; ++ct)
#pragma unroll
        for (int rti = 0; rti < 2; ++rti)
          acc[ct][rti] += *(const f32x4*)&lsRed_[((swi * 2 + ct) * 2 + rti) * 256 + pos];
    }
  }
}

// Persistent recurrence: 96 wgs x 512 thr. Weights LDS-resident (fence-immune).
// 2 device-barrier rounds per timestep; layer0 t=m pipelined vs layer1 t=m-1.
__launch_bounds__(512, 2)
__global__ void k_recur(
    const float* __restrict__ Wr, const float* __restrict__ Wz, const float* __restrict__ Wh,
    const float* __restrict__ Wrb, const float* __restrict__ Wzb, const float* __restrict__ Whb,
    const short* __restrict__ XeHi, const short* __restrict__ XeLo,
    short* X1Hi, short* X1Lo, _Float16* X1f16,
    short* h0Hi, short* h0Lo,
    short* rh0Hi, short* rh0Lo, short* rh1Hi, short* rh1Lo,
    float* z0, float* z1, float* hidOut, unsigned* bar) {
  __shared__ short lsHi[32 * 1024];     // 64 KB: wg's 32 weight rows, bf16-hi
  __shared__ short lsLo[32 * 1024];     // 64 KB: bf16-lo
  __shared__ float lsRed[6 * 2 * 2 * 256];  // 24 KB: cross-wave reduce scratch

  const int wg = blockIdx.x;
  const int tid = threadIdx.x;
  const int wave = tid >> 6, lane = tid & 63, l15 = lane & 15, lq = lane >> 4;
  const bool isA = (wg < 64);
  const int layer = isA ? (wg >> 5) : ((wg - 64) >> 4);
  const int jc = isA ? (wg & 31) * 32 : ((wg - 64) & 15) * 32;

  // ---- stage this wg's weight slice into LDS (split + swizzle), once ----
  for (int i = tid; i < 8192; i += 512) {
    const int j = i >> 8;                // local out-row 0..31
    const int k4 = (i & 255) << 2;       // k 0..1020 step 4
    const float* src;
    if (isA) {
      const int g = jc + j;
      src = (g < 512) ? (Wr + ((size_t)(layer * 512 + g)) * 1024 + k4)
                      : (Wz + ((size_t)(layer * 512 + g - 512)) * 1024 + k4);
    } else {
      src = Wh + ((size_t)(layer * 512 + jc + j)) * 1024 + k4;
    }
    f32x4 v = *(const f32x4*)src;
    s16x4 h4, l4;
#pragma unroll
    for (int q = 0; q < 4; ++q) { short hi, lo; split2(v[q], &hi, &lo); h4[q] = hi; l4[q] = lo; }
    const int els = (j * 1024 + k4) ^ ((j & 7) << 3);
    *(s16x4*)&lsHi[els] = h4;
    *(s16x4*)&lsLo[els] = l4;
  }
  // per-lane bias preload (fence-immune registers)
  float biasL0, biasL1;
  {
    const int j0 = jc + l15, j1 = jc + 16 + l15;
    if (isA) {
      const float* br = Wrb + layer * 512;
      const float* bz = Wzb + layer * 512;
      biasL0 = (j0 < 512) ? br[j0] : bz[j0 - 512];
      biasL1 = (j1 < 512) ? br[j1] : bz[j1 - 512];
    } else {
      const float* bh = Whb + layer * 512;
      biasL0 = bh[j0]; biasL1 = bh[j1];
    }
  }
  __syncthreads();

  unsigned round = 0;
  for (int m = 0; m <= NT; ++m) {
    // ================= phase A: r,z gates =================
    if (isA && ((layer == 0 && m < NT) || (layer == 1 && m >= 1))) {
      const short *aLoH_, *aLoL_, *aHiH_, *aHiL_;
      short *rhH_, *rhL_; float* zOut_;
      if (layer == 0) {
        const int t = m;
        aLoH_ = XeHi + (size_t)t * NB * NE; aLoL_ = XeLo + (size_t)t * NB * NE;
        aHiH_ = h0Hi + (size_t)(m & 1) * SZ_H; aHiL_ = h0Lo + (size_t)(m & 1) * SZ_H;
        rhH_ = rh0Hi; rhL_ = rh0Lo; zOut_ = z0;
      } else {
        const int t = m - 1;
        aLoH_ = h0Hi + (size_t)(m & 1) * SZ_H; aLoL_ = h0Lo + (size_t)(m & 1) * SZ_H;
        aHiH_ = X1Hi + (size_t)t * SZ_H; aHiL_ = X1Lo + (size_t)t * SZ_H;
        rhH_ = rh1Hi; rhL_ = rh1Lo; zOut_ = z1;
      }
      f32x4 acc[2][2];
      phase_mma_reduce(aLoH_, aLoL_, aHiH_, aHiL_, lsHi, lsLo, lsRed,
                       acc, wave, l15, lq);
      if (wave < 2) {
#pragma unroll
        for (int ct = 0; ct < 2; ++ct) {
          const int j = jc + ct * 16 + l15;
          const float bv = ct ? biasL1 : biasL0;
#pragma unroll
          for (int rti = 0; rti < 2; ++rti)
#pragma unroll
            for (int r = 0; r < 4; ++r) {
              const int b = (wave * 2 + rti) * 16 + lq * 4 + r;
              const float pre = acc[ct][rti][r] + bv;
              const float s = 1.0f / (1.0f + __expf(-pre));
              if (j < 512) {
                const float hv = bf2f((unsigned short)aHiH_[b * 512 + j]) +
                                 bf2f((unsigned short)aHiL_[b * 512 + j]);
                short hi, lo; split2(s * hv, &hi, &lo);
                rhH_[b * 512 + j] = hi; rhL_[b * 512 + j] = lo;
              } else {
                zOut_[b * 512 + (j - 512)] = s;
              }
            }
        }
      }
    }
    ++round; gbar(bar, round * (unsigned)NWG);

    // ================= phase B: candidate + state update =================
    if (!isA && ((layer == 0 && m < NT) || (layer == 1 && m >= 1))) {
      const short *aLoH_, *aLoL_, *aHiH_, *aHiL_, *hOldH_, *hOldL_;
      short *hNewH_, *hNewL_;
      const float* zIn_;
      _Float16* xf16_ = nullptr; float* hidOut_ = nullptr;
      if (layer == 0) {
        const int t = m;
        aLoH_ = XeHi + (size_t)t * NB * NE; aLoL_ = XeLo + (size_t)t * NB * NE;
        aHiH_ = rh0Hi; aHiL_ = rh0Lo;
        hOldH_ = h0Hi + (size_t)(m & 1) * SZ_H; hOldL_ = h0Lo + (size_t)(m & 1) * SZ_H;
        hNewH_ = h0Hi + (size_t)((m + 1) & 1) * SZ_H; hNewL_ = h0Lo + (size_t)((m + 1) & 1) * SZ_H;
        zIn_ = z0;
        if (m == NT - 1) hidOut_ = hidOut;
      } else {
        const int t = m - 1;
        aLoH_ = h0Hi + (size_t)(m & 1) * SZ_H; aLoL_ = h0Lo + (size_t)(m & 1) * SZ_H;
        aHiH_ = rh1Hi; aHiL_ = rh1Lo;
        hOldH_ = X1Hi + (size_t)t * SZ_H; hOldL_ = X1Lo + (size_t)t * SZ_H;
        hNewH_ = X1Hi + (size_t)(t + 1) * SZ_H; hNewL_ = X1Lo + (size_t)(t + 1) * SZ_H;
        zIn_ = z1;
        xf16_ = X1f16 + (size_t)t * SZ_H;
        if (m == NT) hidOut_ = hidOut + SZ_H;
      }
      f32x4 acc[2][2];
      phase_mma_reduce(aLoH_, aLoL_, aHiH_, aHiL_, lsHi, lsLo, lsRed,
                       acc, wave, l15, lq);
      if (wave < 2) {
#pragma unroll
        for (int ct = 0; ct < 2; ++ct) {
          const int j = jc + ct * 16 + l15;
          const float bv = ct ? biasL1 : biasL0;
#pragma unroll
          for (int rti = 0; rti < 2; ++rti)
#pragma unroll
            for (int r = 0; r < 4; ++r) {
              const int b = (wave * 2 + rti) * 16 + lq * 4 + r;
              const float pre = acc[ct][rti][r] + bv;
              const float hh = tanhf(pre);
              const float z = zIn_[b * 512 + j];
              const float ho = bf2f((unsigned short)hOldH_[b * 512 + j]) +
                               bf2f((unsigned short)hOldL_[b * 512 + j]);
              const float hn = (1.0f - z) * ho + z * hh;
              short hi, lo; split2(hn, &hi, &lo);
              hNewH_[b * 512 + j] = hi; hNewL_[b * 512 + j] = lo;
              if (xf16_)   xf16_[b * 512 + j] = (_Float16)hn;
              if (hidOut_) hidOut_[b * 512 + j] = hn;
            }
        }
      }
    }
    ++round; gbar(bar, round * (unsigned)NWG);
  }
}

// ---------------- final logits GEMM: C[4096,32000] = X1f16 @ OWf^T + bias ----------------
__launch_bounds__(256, 2)
__global__ void k_gemm(const _Float16* __restrict__ A, const _Float16* __restrict__ Bw,
                       const float* __restrict__ bias, float* __restrict__ C) {
  __shared__ _Float16 lsA[128 * 64];
  __shared__ _Float16 lsB[128 * 64];
  const int bm = blockIdx.x;   // 0..31  (M blocks)
  const int bn = blockIdx.y;   // 0..249 (N blocks)
  const int tid = threadIdx.x;
  const int wave = tid >> 6, lane = tid & 63;
  const int l15 = lane & 15, lq = lane >> 4;
  const int wr = (wave >> 1) * 64, wc = (wave & 1) * 64;
  f32x4 acc[4][4] = {};
  const size_t arow0 = (size_t)bm * 128;
  const size_t brow0 = (size_t)bn * 128;

  for (int kb = 0; kb < 512; kb += 64) {
#pragma unroll
    for (int i = 0; i < 4; ++i) {
      int c = tid + i * 256;
      int row = c >> 3, kc = (c & 7) * 8;
      f16x8 va = *(const f16x8*)(A  + (arow0 + row) * 512 + kb + kc);
      f16x8 vb = *(const f16x8*)(Bw + (brow0 + row) * 512 + kb + kc);
      int el = (row * 64 + kc) ^ ((row & 7) << 3);
      *(f16x8*)&lsA[el] = va;
      *(f16x8*)&lsB[el] = vb;
    }
    __syncthreads();
#pragma unroll
    for (int k0 = 0; k0 < 64; k0 += 32) {
      const int kk = k0 + lq * 8;
      f16x8 af[4], bf_[4];
#pragma unroll
      for (int i = 0; i < 4; ++i) {
        int ra = wr + i * 16 + l15;
        af[i]  = *(const f16x8*)&lsA[(ra * 64 + kk) ^ ((ra & 7) << 3)];
        int rb = wc + i * 16 + l15;
        bf_[i] = *(const f16x8*)&lsB[(rb * 64 + kk) ^ ((rb & 7) << 3)];
      }
#pragma unroll
      for (int i = 0; i < 4; ++i)
#pragma unroll
        for (int jt = 0; jt < 4; ++jt)
          acc[i][jt] = mma_f16(af[i], bf_[jt], acc[i][jt]);
    }
    __syncthreads();
  }
#pragma unroll
  for (int i = 0; i < 4; ++i) {
#pragma unroll
    for (int jt = 0; jt < 4; ++jt) {
      const size_t col = brow0 + wc + jt * 16 + l15;
      const float bval = bias[col];
#pragma unroll
      for (int r = 0; r < 4; ++r) {
        const size_t row = arow0 + wr + i * 16 + lq * 4 + r;
        C[row * (size_t)NV + col] = acc[i][jt][r] + bval;
      }
    }
  }
}

// ---------------- launcher ----------------
extern "C" void kernel_launch(void* const* d_in, const int* in_sizes, int n_in,
                              void* d_out, int out_size, void* d_ws, size_t ws_size,
                              hipStream_t stream) {
  (void)in_sizes; (void)n_in; (void)out_size; (void)ws_size;
  const int*   toks = (const int*)d_in[0];
  const float* hid  = (const float*)d_in[1];
  const float* emb  = (const float*)d_in[2];
  const float* Wr   = (const float*)d_in[3];
  const float* Wrb  = (const float*)d_in[4];
  const float* Wz   = (const float*)d_in[5];
  const float* Wzb  = (const float*)d_in[6];
  const float* Wh   = (const float*)d_in[7];
  const float* Whb  = (const float*)d_in[8];
  const float* outw = (const float*)d_in[9];
  const float* outb = (const float*)d_in[10];
  float* out = (float*)d_out;

  char* base = (char*)d_ws;
  size_t off = 0;
  auto carve = [&](size_t bytes) -> char* {
    char* r = base + off;
    off = (off + bytes + 255) & ~(size_t)255;
    return r;
  };
  _Float16* OWf   = (_Float16*)carve(SZ_OW * 2);
  short*    XeHi  = (short*)carve(SZ_XE * 2);
  short*    XeLo  = (short*)carve(SZ_XE * 2);
  short*    X1Hi  = (short*)carve((size_t)(NT + 1) * SZ_H * 2);
  short*    X1Lo  = (short*)carve((size_t)(NT + 1) * SZ_H * 2);
  _Float16* X1f16 = (_Float16*)carve((size_t)NT * SZ_H * 2);
  short*    h0Hi  = (short*)carve(2 * SZ_H * 2);
  short*    h0Lo  = (short*)carve(2 * SZ_H * 2);
  short*    rh0Hi = (short*)carve(SZ_H * 2);
  short*    rh0Lo = (short*)carve(SZ_H * 2);
  short*    rh1Hi = (short*)carve(SZ_H * 2);
  short*    rh1Lo = (short*)carve(SZ_H * 2);
  float*    z0    = (float*)carve(SZ_H * 4);
  float*    z1    = (float*)carve(SZ_H * 4);
  unsigned* bar   = (unsigned*)carve(256);

  hipMemsetAsync(bar, 0, 256, stream);

  k_prep<<<2048, 256, 0, stream>>>(outw, toks, emb, hid,
                                   OWf, XeHi, XeLo, X1Hi, X1Lo, h0Hi, h0Lo);

  k_recur<<<NWG, 512, 0, stream>>>(Wr, Wz, Wh, Wrb, Wzb, Whb,
                                   XeHi, XeLo,
                                   X1Hi, X1Lo, X1f16, h0Hi, h0Lo,
                                   rh0Hi, rh0Lo, rh1Hi, rh1Lo, z0, z1,
                                   out + LOGITS, bar);

  dim3 g(32, 250);
  k_gemm<<<g, 256, 0, stream>>>(X1f16, OWf, outb, out);
}

// Round 3
// 2428.738 us; speedup vs baseline: 1.9491x; 1.9491x over previous
//
#include <hip/hip_runtime.h>

// ---------------- constants ----------------
constexpr int NT = 64;     // timesteps
constexpr int NB = 64;     // batch
constexpr int NV = 32000;  // vocab
constexpr int NE = 512;    // embed
constexpr int NH = 512;    // hidden
constexpr int NWG = 96;    // 64 A-wgs + 32 B-wgs, all resident (1 wg/CU, LDS-bound)

constexpr size_t SZ_OW  = (size_t)NV * NE;          // 16,384,000
constexpr size_t SZ_XE  = (size_t)NT * NB * NE;     // 2,097,152
constexpr size_t SZ_H   = (size_t)NB * NH;          // 32,768
constexpr size_t LOGITS = (size_t)NT * NB * NV;     // 131,072,000

typedef float f32x4 __attribute__((ext_vector_type(4)));
typedef short bf16x8 __attribute__((ext_vector_type(8)));
typedef short s16x4 __attribute__((ext_vector_type(4)));
typedef _Float16 f16x8 __attribute__((ext_vector_type(8)));

// ---------------- helpers ----------------
__device__ __forceinline__ unsigned short f2bf(float x) {
  unsigned u = __float_as_uint(x);
  u += 0x7FFFu + ((u >> 16) & 1u);            // RNE
  return (unsigned short)(u >> 16);
}
__device__ __forceinline__ float bf2f(unsigned short s) {
  return __uint_as_float(((unsigned)s) << 16);
}
__device__ __forceinline__ void split2(float v, short* hi, short* lo) {
  unsigned short h = f2bf(v);
  *hi = (short)h;
  *lo = (short)f2bf(v - bf2f(h));
}
__device__ __forceinline__ f32x4 mma_bf16(bf16x8 a, bf16x8 b, f32x4 c) {
  return __builtin_amdgcn_mfma_f32_16x16x32_bf16(a, b, c, 0, 0, 0);
}
__device__ __forceinline__ f32x4 mma_f16(f16x8 a, f16x8 b, f32x4 c) {
  return __builtin_amdgcn_mfma_f32_16x16x32_f16(a, b, c, 0, 0, 0);
}

// write-through-to-LLC stores (bypass L1/L2 dirty state; LLC = coherence point)
__device__ __forceinline__ void st_sc16(short* p, short v) {
  asm volatile("global_store_short %0, %1, off sc0 sc1" :: "v"(p), "v"(v) : "memory");
}
__device__ __forceinline__ void st_sc32(float* p, float v) {
  asm volatile("global_store_dword %0, %1, off sc0 sc1" :: "v"(p), "v"(v) : "memory");
}

// Fence-free device barrier: relaxed atomics only (NO buffer_inv / buffer_wbl2).
// Ordering: sc0sc1 stores reach LLC; vmcnt(0) drains them before the signal.
// Consumers read fresh (never-before-touched) addresses -> cold miss -> LLC.
__device__ __forceinline__ void gbar(unsigned* bar, unsigned target) {
  asm volatile("s_waitcnt vmcnt(0)" ::: "memory");
  __syncthreads();
  if (threadIdx.x == 0) {
    __hip_atomic_fetch_add(bar, 1u, __ATOMIC_RELAXED, __HIP_MEMORY_SCOPE_AGENT);
    while (__hip_atomic_load(bar, __ATOMIC_RELAXED, __HIP_MEMORY_SCOPE_AGENT) < target)
      __builtin_amdgcn_s_sleep(1);
  }
  __syncthreads();
}

// ---------------- prep: OW cast, embed split, init state ----------------
__global__ void k_prep(
    const float* __restrict__ outw, const int* __restrict__ toks,
    const float* __restrict__ emb, const float* __restrict__ hid,
    _Float16* OWf, short* XeHi, short* XeLo,
    short* X1Hi, short* X1Lo, short* h0Hi, short* h0Lo) {
  const size_t stride = (size_t)gridDim.x * blockDim.x;
  const size_t N1 = SZ_OW, N2 = N1 + SZ_XE, N3 = N2 + SZ_H, N4 = N3 + SZ_H;
  for (size_t x = (size_t)blockIdx.x * blockDim.x + threadIdx.x; x < N4; x += stride) {
    if (x < N1) {
      OWf[x] = (_Float16)outw[x];
    } else if (x < N2) {
      size_t p = x - N1;
      size_t r = p >> 9, c = p & 511u;
      int tok = toks[r];
      float v = emb[(size_t)tok * 512 + c];
      short hi, lo; split2(v, &hi, &lo);
      XeHi[p] = hi; XeLo[p] = lo;
    } else if (x < N3) {
      size_t p = x - N2;
      short hi, lo; split2(hid[p], &hi, &lo);
      h0Hi[p] = hi; h0Lo[p] = lo;          // h0 slot 0
    } else {
      size_t p = x - N3;
      short hi, lo; split2(hid[SZ_H + p], &hi, &lo);
      X1Hi[p] = hi; X1Lo[p] = lo;          // X1 slot 0
    }
  }
}

// ---------------- recurrence MMA core ----------------
__device__ __forceinline__ void mma_block(
    const short* __restrict__ pAH, const short* __restrict__ pAL,
    int kloc0, int kkGlob0,
    const short* lsHi_, const short* lsLo_,
    f32x4 (&accH)[2][2], f32x4 (&accL)[2][2],
    int l15, int lq, int rhalf) {
  const int r0 = (rhalf * 2) * 16 + l15;
  const int r1 = (rhalf * 2 + 1) * 16 + l15;
#pragma unroll 4
  for (int i = 0; i < 8; ++i) {
    const int kk = kkGlob0 + i * 32 + lq * 8;   // global k (LDS index)
    const int ka = kloc0 + i * 32 + lq * 8;     // local k within act array
    const int e0 = (l15 * 1024 + kk) ^ ((l15 & 7) << 3);
    const int e1 = ((16 + l15) * 1024 + kk) ^ ((l15 & 7) << 3);
    bf16x8 bh0 = *(const bf16x8*)&lsHi_[e0];
    bf16x8 bl0 = *(const bf16x8*)&lsLo_[e0];
    bf16x8 bh1 = *(const bf16x8*)&lsHi_[e1];
    bf16x8 bl1 = *(const bf16x8*)&lsLo_[e1];
    bf16x8 a0h = *(const bf16x8*)&pAH[r0 * 512 + ka];
    bf16x8 a0l = *(const bf16x8*)&pAL[r0 * 512 + ka];
    bf16x8 a1h = *(const bf16x8*)&pAH[r1 * 512 + ka];
    bf16x8 a1l = *(const bf16x8*)&pAL[r1 * 512 + ka];
    accH[0][0] = mma_bf16(a0h, bh0, accH[0][0]);
    accH[0][1] = mma_bf16(a1h, bh0, accH[0][1]);
    accH[1][0] = mma_bf16(a0h, bh1, accH[1][0]);
    accH[1][1] = mma_bf16(a1h, bh1, accH[1][1]);
    accL[0][0] = mma_bf16(a0l, bh0, accL[0][0]);
    accL[0][1] = mma_bf16(a1l, bh0, accL[0][1]);
    accL[1][0] = mma_bf16(a0l, bh1, accL[1][0]);
    accL[1][1] = mma_bf16(a1l, bh1, accL[1][1]);
    accL[0][0] = mma_bf16(a0h, bl0, accL[0][0]);
    accL[0][1] = mma_bf16(a1h, bl0, accL[0][1]);
    accL[1][0] = mma_bf16(a0h, bl1, accL[1][0]);
    accL[1][1] = mma_bf16(a1h, bl1, accL[1][1]);
  }
}

// Full-wg phase: MMA + cross-wave k-reduction. After return, waves 0,1 hold
// final sums in acc (wave w owns row-tiles 2w, 2w+1 via rti; cols jc+ct*16+l15).
__device__ __forceinline__ void phase_mma_reduce(
    const short* aLoH, const short* aLoL,
    const short* aHiH, const short* aHiL,
    const short* lsHi_, const short* lsLo_, float* lsRed_,
    f32x4 (&acc)[2][2], int wave, int l15, int lq) {
  const int khalf = wave >> 1, rhalf = wave & 1;
  f32x4 accH[2][2] = {}, accL[2][2] = {};
  const short* pAH = (khalf < 2) ? aLoH : aHiH;
  const short* pAL = (khalf < 2) ? aLoL : aHiL;
  mma_block(pAH, pAL, (khalf & 1) * 256, khalf * 256, lsHi_, lsLo_,
            accH, accL, l15, lq, rhalf);
#pragma unroll
  for (int ct = 0; ct < 2; ++ct)
#pragma unroll
    for (int rti = 0; rti < 2; ++rti) acc[ct][rti] = accH[ct][rti] + accL[ct][rti];
  const int pos = l15 * 16 + lq * 4;
  if (wave >= 2) {
#pragma unroll
    for (int ct = 0; ct < 2; ++ct)
#pragma unroll
      for (int rti = 0; rti < 2; ++rti)
        *(f32x4*)&lsRed_[(((wave - 2) * 2 + ct) * 2 + rti) * 256 + pos] = acc[ct][rti];
  }
  __syncthreads();
  if (wave < 2) {
#pragma unroll
    for (int s = 0; s < 3; ++s) {
      const int swi = rhalf + 2 * s;
#pragma unroll
      for (int ct = 0; ct < 2; ++ct)
#pragma unroll
        for (int rti = 0; rti < 2; ++rti)
          acc[ct][rti] += *(const f32x4*)&lsRed_[((swi * 2 + ct) * 2 + rti) * 256 + pos];
    }
  }
}

// Persistent recurrence: 96 wgs x 512 thr. Weights LDS-resident.
// All cross-wg buffers are PER-TIMESTEP (never reused) -> consumer caches can
// never be stale; producers write through to LLC (sc0sc1); barrier is fence-free.
__launch_bounds__(512, 2)
__global__ void k_recur(
    const float* __restrict__ Wr, const float* __restrict__ Wz, const float* __restrict__ Wh,
    const float* __restrict__ Wrb, const float* __restrict__ Wzb, const float* __restrict__ Whb,
    const short* __restrict__ XeHi, const short* __restrict__ XeLo,
    short* X1Hi, short* X1Lo, _Float16* X1f16,
    short* h0Hi, short* h0Lo,
    short* rh0Hi, short* rh0Lo, short* rh1Hi, short* rh1Lo,
    float* z0, float* z1, float* hidOut, unsigned* bar) {
  __shared__ short lsHi[32 * 1024];     // 64 KB
  __shared__ short lsLo[32 * 1024];     // 64 KB
  __shared__ float lsRed[6 * 2 * 2 * 256];  // 24 KB

  const int wg = blockIdx.x;
  const int tid = threadIdx.x;
  const int wave = tid >> 6, lane = tid & 63, l15 = lane & 15, lq = lane >> 4;
  const bool isA = (wg < 64);
  const int layer = isA ? (wg >> 5) : ((wg - 64) >> 4);
  const int jc = isA ? (wg & 31) * 32 : ((wg - 64) & 15) * 32;

  // ---- stage this wg's weight slice into LDS (split + swizzle), once ----
  for (int i = tid; i < 8192; i += 512) {
    const int j = i >> 8;
    const int k4 = (i & 255) << 2;
    const float* src;
    if (isA) {
      const int g = jc + j;
      src = (g < 512) ? (Wr + ((size_t)(layer * 512 + g)) * 1024 + k4)
                      : (Wz + ((size_t)(layer * 512 + g - 512)) * 1024 + k4);
    } else {
      src = Wh + ((size_t)(layer * 512 + jc + j)) * 1024 + k4;
    }
    f32x4 v = *(const f32x4*)src;
    s16x4 h4, l4;
#pragma unroll
    for (int q = 0; q < 4; ++q) { short hi, lo; split2(v[q], &hi, &lo); h4[q] = hi; l4[q] = lo; }
    const int els = (j * 1024 + k4) ^ ((j & 7) << 3);
    *(s16x4*)&lsHi[els] = h4;
    *(s16x4*)&lsLo[els] = l4;
  }
  float biasL0, biasL1;
  {
    const int j0 = jc + l15, j1 = jc + 16 + l15;
    if (isA) {
      const float* br = Wrb + layer * 512;
      const float* bz = Wzb + layer * 512;
      biasL0 = (j0 < 512) ? br[j0] : bz[j0 - 512];
      biasL1 = (j1 < 512) ? br[j1] : bz[j1 - 512];
    } else {
      const float* bh = Whb + layer * 512;
      biasL0 = bh[j0]; biasL1 = bh[j1];
    }
  }
  __syncthreads();

  unsigned round = 0;
  for (int m = 0; m <= NT; ++m) {
    // ================= phase A: r,z gates =================
    if (isA && ((layer == 0 && m < NT) || (layer == 1 && m >= 1))) {
      const int t = (layer == 0) ? m : (m - 1);
      const short *aLoH_, *aLoL_, *aHiH_, *aHiL_;
      short *rhH_, *rhL_; float* zOut_;
      if (layer == 0) {
        aLoH_ = XeHi + (size_t)t * SZ_H; aLoL_ = XeLo + (size_t)t * SZ_H;
        aHiH_ = h0Hi + (size_t)m * SZ_H; aHiL_ = h0Lo + (size_t)m * SZ_H;
        rhH_ = rh0Hi + (size_t)t * SZ_H; rhL_ = rh0Lo + (size_t)t * SZ_H;
        zOut_ = z0 + (size_t)t * SZ_H;
      } else {
        aLoH_ = h0Hi + (size_t)m * SZ_H; aLoL_ = h0Lo + (size_t)m * SZ_H;  // = layer0 out at t
        aHiH_ = X1Hi + (size_t)t * SZ_H; aHiL_ = X1Lo + (size_t)t * SZ_H;
        rhH_ = rh1Hi + (size_t)t * SZ_H; rhL_ = rh1Lo + (size_t)t * SZ_H;
        zOut_ = z1 + (size_t)t * SZ_H;
      }
      f32x4 acc[2][2];
      phase_mma_reduce(aLoH_, aLoL_, aHiH_, aHiL_, lsHi, lsLo, lsRed,
                       acc, wave, l15, lq);
      if (wave < 2) {
#pragma unroll
        for (int ct = 0; ct < 2; ++ct) {
          const int j = jc + ct * 16 + l15;
          const float bv = ct ? biasL1 : biasL0;
#pragma unroll
          for (int rti = 0; rti < 2; ++rti)
#pragma unroll
            for (int r = 0; r < 4; ++r) {
              const int b = (wave * 2 + rti) * 16 + lq * 4 + r;
              const float pre = acc[ct][rti][r] + bv;
              const float s = 1.0f / (1.0f + __expf(-pre));
              if (j < 512) {
                const float hv = bf2f((unsigned short)aHiH_[b * 512 + j]) +
                                 bf2f((unsigned short)aHiL_[b * 512 + j]);
                short hi, lo; split2(s * hv, &hi, &lo);
                st_sc16(rhH_ + b * 512 + j, hi);
                st_sc16(rhL_ + b * 512 + j, lo);
              } else {
                st_sc32(zOut_ + b * 512 + (j - 512), s);
              }
            }
        }
      }
    }
    ++round; gbar(bar, round * (unsigned)NWG);

    // ================= phase B: candidate + state update =================
    if (!isA && ((layer == 0 && m < NT) || (layer == 1 && m >= 1))) {
      const int t = (layer == 0) ? m : (m - 1);
      const short *aLoH_, *aLoL_, *aHiH_, *aHiL_, *hOldH_, *hOldL_;
      short *hNewH_, *hNewL_;
      const float* zIn_;
      _Float16* xf16_ = nullptr; float* hidOut_ = nullptr;
      if (layer == 0) {
        aLoH_ = XeHi + (size_t)t * SZ_H; aLoL_ = XeLo + (size_t)t * SZ_H;
        aHiH_ = rh0Hi + (size_t)t * SZ_H; aHiL_ = rh0Lo + (size_t)t * SZ_H;
        hOldH_ = h0Hi + (size_t)m * SZ_H; hOldL_ = h0Lo + (size_t)m * SZ_H;
        hNewH_ = h0Hi + (size_t)(m + 1) * SZ_H; hNewL_ = h0Lo + (size_t)(m + 1) * SZ_H;
        zIn_ = z0 + (size_t)t * SZ_H;
        if (m == NT - 1) hidOut_ = hidOut;
      } else {
        aLoH_ = h0Hi + (size_t)m * SZ_H; aLoL_ = h0Lo + (size_t)m * SZ_H;
        aHiH_ = rh1Hi + (size_t)t * SZ_H; aHiL_ = rh1Lo + (size_t)t * SZ_H;
        hOldH_ = X1Hi + (size_t)t * SZ_H; hOldL_ = X1Lo + (size_t)t * SZ_H;
        hNewH_ = X1Hi + (size_t)(t + 1) * SZ_H; hNewL_ = X1Lo + (size_t)(t + 1) * SZ_H;
        zIn_ = z1 + (size_t)t * SZ_H;
        xf16_ = X1f16 + (size_t)t * SZ_H;
        if (m == NT) hidOut_ = hidOut + SZ_H;
      }
      f32x4 acc[2][2];
      phase_mma_reduce(aLoH_, aLoL_, aHiH_, aHiL_, lsHi, lsLo, lsRed,
                       acc, wave, l15, lq);
      if (wave < 2) {
#pragma unroll
        for (int ct = 0; ct < 2; ++ct) {
          const int j = jc + ct * 16 + l15;
          const float bv = ct ? biasL1 : biasL0;
#pragma unroll
          for (int rti = 0; rti < 2; ++rti)
#pragma unroll
            for (int r = 0; r < 4; ++r) {
              const int b = (wave * 2 + rti) * 16 + lq * 4 + r;
              const float pre = acc[ct][rti][r] + bv;
              const float hh = tanhf(pre);
              const float z = zIn_[b * 512 + j];
              const float ho = bf2f((unsigned short)hOldH_[b * 512 + j]) +
                               bf2f((unsigned short)hOldL_[b * 512 + j]);
              const float hn = (1.0f - z) * ho + z * hh;
              short hi, lo; split2(hn, &hi, &lo);
              st_sc16(hNewH_ + b * 512 + j, hi);
              st_sc16(hNewL_ + b * 512 + j, lo);
              if (xf16_)   xf16_[b * 512 + j] = (_Float16)hn;   // consumed post-kernel
              if (hidOut_) hidOut_[b * 512 + j] = hn;           // consumed post-kernel
            }
        }
      }
    }
    ++round; gbar(bar, round * (unsigned)NWG);
  }
}

// ---------------- final logits GEMM: C[4096,32000] = X1f16 @ OWf^T + bias ----------------
__launch_bounds__(256, 2)
__global__ void k_gemm(const _Float16* __restrict__ A, const _Float16* __restrict__ Bw,
                       const float* __restrict__ bias, float* __restrict__ C) {
  __shared__ _Float16 lsA[128 * 64];
  __shared__ _Float16 lsB[128 * 64];
  const int bm = blockIdx.x;
  const int bn = blockIdx.y;
  const int tid = threadIdx.x;
  const int wave = tid >> 6, lane = tid & 63;
  const int l15 = lane & 15, lq = lane >> 4;
  const int wr = (wave >> 1) * 64, wc = (wave & 1) * 64;
  f32x4 acc[4][4] = {};
  const size_t arow0 = (size_t)bm * 128;
  const size_t brow0 = (size_t)bn * 128;

  for (int kb = 0; kb < 512; kb += 64) {
#pragma unroll
    for (int i = 0; i < 4; ++i) {
      int c = tid + i * 256;
      int row = c >> 3, kc = (c & 7) * 8;
      f16x8 va = *(const f16x8*)(A  + (arow0 + row) * 512 + kb + kc);
      f16x8 vb = *(const f16x8*)(Bw + (brow0 + row) * 512 + kb + kc);
      int el = (row * 64 + kc) ^ ((row & 7) << 3);
      *(f16x8*)&lsA[el] = va;
      *(f16x8*)&lsB[el] = vb;
    }
    __syncthreads();
#pragma unroll
    for (int k0 = 0; k0 < 64; k0 += 32) {
      const int kk = k0 + lq * 8;
      f16x8 af[4], bf_[4];
#pragma unroll
      for (int i = 0; i < 4; ++i) {
        int ra = wr + i * 16 + l15;
        af[i]  = *(const f16x8*)&lsA[(ra * 64 + kk) ^ ((ra & 7) << 3)];
        int rb = wc + i * 16 + l15;
        bf_[i] = *(const f16x8*)&lsB[(rb * 64 + kk) ^ ((rb & 7) << 3)];
      }
#pragma unroll
      for (int i = 0; i < 4; ++i)
#pragma unroll
        for (int jt = 0; jt < 4; ++jt)
          acc[i][jt] = mma_f16(af[i], bf_[jt], acc[i][jt]);
    }
    __syncthreads();
  }
#pragma unroll
  for (int i = 0; i < 4; ++i) {
#pragma unroll
    for (int jt = 0; jt < 4; ++jt) {
      const size_t col = brow0 + wc + jt * 16 + l15;
      const float bval = bias[col];
#pragma unroll
      for (int r = 0; r < 4; ++r) {
        const size_t row = arow0 + wr + i * 16 + lq * 4 + r;
        C[row * (size_t)NV + col] = acc[i][jt][r] + bval;
      }
    }
  }
}

// ---------------- launcher ----------------
extern "C" void kernel_launch(void* const* d_in, const int* in_sizes, int n_in,
                              void* d_out, int out_size, void* d_ws, size_t ws_size,
                              hipStream_t stream) {
  (void)in_sizes; (void)n_in; (void)out_size; (void)ws_size;
  const int*   toks = (const int*)d_in[0];
  const float* hid  = (const float*)d_in[1];
  const float* emb  = (const float*)d_in[2];
  const float* Wr   = (const float*)d_in[3];
  const float* Wrb  = (const float*)d_in[4];
  const float* Wz   = (const float*)d_in[5];
  const float* Wzb  = (const float*)d_in[6];
  const float* Wh   = (const float*)d_in[7];
  const float* Whb  = (const float*)d_in[8];
  const float* outw = (const float*)d_in[9];
  const float* outb = (const float*)d_in[10];
  float* out = (float*)d_out;

  char* base = (char*)d_ws;
  size_t off = 0;
  auto carve = [&](size_t bytes) -> char* {
    char* r = base + off;
    off = (off + bytes + 255) & ~(size_t)255;
    return r;
  };
  _Float16* OWf   = (_Float16*)carve(SZ_OW * 2);
  short*    XeHi  = (short*)carve(SZ_XE * 2);
  short*    XeLo  = (short*)carve(SZ_XE * 2);
  // per-timestep versioned cross-wg buffers (never reuse an address)
  short*    X1Hi  = (short*)carve((size_t)(NT + 1) * SZ_H * 2);
  short*    X1Lo  = (short*)carve((size_t)(NT + 1) * SZ_H * 2);
  _Float16* X1f16 = (_Float16*)carve((size_t)NT * SZ_H * 2);
  short*    h0Hi  = (short*)carve((size_t)(NT + 1) * SZ_H * 2);
  short*    h0Lo  = (short*)carve((size_t)(NT + 1) * SZ_H * 2);
  short*    rh0Hi = (short*)carve((size_t)NT * SZ_H * 2);
  short*    rh0Lo = (short*)carve((size_t)NT * SZ_H * 2);
  short*    rh1Hi = (short*)carve((size_t)NT * SZ_H * 2);
  short*    rh1Lo = (short*)carve((size_t)NT * SZ_H * 2);
  float*    z0    = (float*)carve((size_t)NT * SZ_H * 4);
  float*    z1    = (float*)carve((size_t)NT * SZ_H * 4);
  unsigned* bar   = (unsigned*)carve(256);

  hipMemsetAsync(bar, 0, 256, stream);

  k_prep<<<2048, 256, 0, stream>>>(outw, toks, emb, hid,
                                   OWf, XeHi, XeLo, X1Hi, X1Lo, h0Hi, h0Lo);

  k_recur<<<NWG, 512, 0, stream>>>(Wr, Wz, Wh, Wrb, Wzb, Whb,
                                   XeHi, XeLo,
                                   X1Hi, X1Lo, X1f16, h0Hi, h0Lo,
                                   rh0Hi, rh0Lo, rh1Hi, rh1Lo, z0, z1,
                                   out + LOGITS, bar);

  dim3 g(32, 250);
  k_gemm<<<g, 256, 0, stream>>>(X1f16, OWf, outb, out);
}

// Round 4
// 2150.840 us; speedup vs baseline: 2.2010x; 1.1292x over previous
//
#include <hip/hip_runtime.h>

// ---------------- constants ----------------
constexpr int NT = 64;     // timesteps
constexpr int NB = 64;     // batch
constexpr int NV = 32000;  // vocab
constexpr int NE = 512;    // embed
constexpr int NH = 512;    // hidden
constexpr int NWG_R = 96;  // recurrence wgs (64 A + 32 B)
constexpr int NWG_G = 128; // gemm consumer wgs
constexpr int NGRP = 8;    // barrier shard groups (wg % 8)
constexpr int GSZ = NWG_R / NGRP;  // 12 wgs per group

constexpr size_t SZ_OW  = (size_t)NV * NE;          // 16,384,000
constexpr size_t SZ_XE  = (size_t)NT * NB * NE;     // 2,097,152
constexpr size_t SZ_H   = (size_t)NB * NH;          // 32,768
constexpr size_t LOGITS = (size_t)NT * NB * NV;     // 131,072,000
constexpr int NTILE = 32 * 250;                     // 8000 gemm tiles

typedef float f32x4 __attribute__((ext_vector_type(4)));
typedef short bf16x8 __attribute__((ext_vector_type(8)));
typedef short s16x4 __attribute__((ext_vector_type(4)));
typedef _Float16 f16x8 __attribute__((ext_vector_type(8)));

// ---------------- helpers ----------------
__device__ __forceinline__ unsigned short f2bf(float x) {
  unsigned u = __float_as_uint(x);
  u += 0x7FFFu + ((u >> 16) & 1u);            // RNE
  return (unsigned short)(u >> 16);
}
__device__ __forceinline__ float bf2f(unsigned short s) {
  return __uint_as_float(((unsigned)s) << 16);
}
__device__ __forceinline__ void split2(float v, short* hi, short* lo) {
  unsigned short h = f2bf(v);
  *hi = (short)h;
  *lo = (short)f2bf(v - bf2f(h));
}
__device__ __forceinline__ f32x4 mma_bf16(bf16x8 a, bf16x8 b, f32x4 c) {
  return __builtin_amdgcn_mfma_f32_16x16x32_bf16(a, b, c, 0, 0, 0);
}
__device__ __forceinline__ f32x4 mma_f16(f16x8 a, f16x8 b, f32x4 c) {
  return __builtin_amdgcn_mfma_f32_16x16x32_f16(a, b, c, 0, 0, 0);
}

// write-through-to-LLC stores (LLC/MALL = chip-level coherence point)
__device__ __forceinline__ void st_sc16(short* p, short v) {
  asm volatile("global_store_short %0, %1, off sc0 sc1" :: "v"(p), "v"(v) : "memory");
}
__device__ __forceinline__ void st_sc32(float* p, float v) {
  asm volatile("global_store_dword %0, %1, off sc0 sc1" :: "v"(p), "v"(v) : "memory");
}
__device__ __forceinline__ void st_sc32u(unsigned* p, unsigned v) {
  asm volatile("global_store_dword %0, %1, off sc0 sc1" :: "v"(p), "v"(v) : "memory");
}
// fresh MALL read, NON-atomic (read port, not the atomic unit)
__device__ __forceinline__ unsigned ld_sc32u(const unsigned* p) {
  unsigned v;
  asm volatile("global_load_dword %0, %1, off sc0 sc1\n\ts_waitcnt vmcnt(0)"
               : "=v"(v) : "v"(p) : "memory");
  return v;
}

// Hierarchical fence-free device barrier for the 96 recurrence wgs.
// Sharded by grp = wg % 8 (pure sharding key; all traffic is MALL-level so
// wg->XCD placement is irrelevant). Hot-path polls are plain sc0sc1 loads
// spread over 9 lines; only 8 RMWs/round touch gctr.
__device__ __forceinline__ void hbar(int grp, unsigned r,
                                     unsigned* lctr, unsigned* release,
                                     unsigned* gctr, unsigned* gmirror) {
  asm volatile("s_waitcnt vmcnt(0)" ::: "memory");  // drain this wave's data stores
  __syncthreads();
  if (threadIdx.x == 0) {
    unsigned old = __hip_atomic_fetch_add(&lctr[grp * 32], 1u, __ATOMIC_RELAXED,
                                          __HIP_MEMORY_SCOPE_AGENT);
    if (old == (unsigned)GSZ * r - 1u) {
      // last of this group: forward group count to global
      unsigned gold = __hip_atomic_fetch_add(gctr, (unsigned)GSZ, __ATOMIC_RELAXED,
                                             __HIP_MEMORY_SCOPE_AGENT);
      if (gold + (unsigned)GSZ == (unsigned)NWG_R * r) {
        st_sc32u(gmirror, r);                 // publish round for gemm wgs
      }
      while (ld_sc32u(gctr) < (unsigned)NWG_R * r)
        __builtin_amdgcn_s_sleep(4);
      st_sc32u(&release[grp * 32], r);        // release my group
    } else {
      while (ld_sc32u(&release[grp * 32]) < r)
        __builtin_amdgcn_s_sleep(2);
    }
  }
  __syncthreads();
}

// ---------------- prep: OW cast, embed split, init state ----------------
__global__ void k_prep(
    const float* __restrict__ outw, const int* __restrict__ toks,
    const float* __restrict__ emb, const float* __restrict__ hid,
    _Float16* OWf, short* XeHi, short* XeLo,
    short* X1Hi, short* X1Lo, short* h0Hi, short* h0Lo) {
  const size_t stride = (size_t)gridDim.x * blockDim.x;
  const size_t N1 = SZ_OW, N2 = N1 + SZ_XE, N3 = N2 + SZ_H, N4 = N3 + SZ_H;
  for (size_t x = (size_t)blockIdx.x * blockDim.x + threadIdx.x; x < N4; x += stride) {
    if (x < N1) {
      OWf[x] = (_Float16)outw[x];
    } else if (x < N2) {
      size_t p = x - N1;
      size_t r = p >> 9, c = p & 511u;
      int tok = toks[r];
      float v = emb[(size_t)tok * 512 + c];
      short hi, lo; split2(v, &hi, &lo);
      XeHi[p] = hi; XeLo[p] = lo;
    } else if (x < N3) {
      size_t p = x - N2;
      short hi, lo; split2(hid[p], &hi, &lo);
      h0Hi[p] = hi; h0Lo[p] = lo;          // h0 slot 0
    } else {
      size_t p = x - N3;
      short hi, lo; split2(hid[SZ_H + p], &hi, &lo);
      X1Hi[p] = hi; X1Lo[p] = lo;          // X1 slot 0
    }
  }
}

// ---------------- recurrence MMA core ----------------
__device__ __forceinline__ void mma_block(
    const short* __restrict__ pAH, const short* __restrict__ pAL,
    int kloc0, int kkGlob0,
    const short* lsHi_, const short* lsLo_,
    f32x4 (&accH)[2][2], f32x4 (&accL)[2][2],
    int l15, int lq, int rhalf) {
  const int r0 = (rhalf * 2) * 16 + l15;
  const int r1 = (rhalf * 2 + 1) * 16 + l15;
#pragma unroll 4
  for (int i = 0; i < 8; ++i) {
    const int kk = kkGlob0 + i * 32 + lq * 8;   // global k (LDS index)
    const int ka = kloc0 + i * 32 + lq * 8;     // local k within act array
    const int e0 = (l15 * 1024 + kk) ^ ((l15 & 7) << 3);
    const int e1 = ((16 + l15) * 1024 + kk) ^ ((l15 & 7) << 3);
    bf16x8 bh0 = *(const bf16x8*)&lsHi_[e0];
    bf16x8 bl0 = *(const bf16x8*)&lsLo_[e0];
    bf16x8 bh1 = *(const bf16x8*)&lsHi_[e1];
    bf16x8 bl1 = *(const bf16x8*)&lsLo_[e1];
    bf16x8 a0h = *(const bf16x8*)&pAH[r0 * 512 + ka];
    bf16x8 a0l = *(const bf16x8*)&pAL[r0 * 512 + ka];
    bf16x8 a1h = *(const bf16x8*)&pAH[r1 * 512 + ka];
    bf16x8 a1l = *(const bf16x8*)&pAL[r1 * 512 + ka];
    accH[0][0] = mma_bf16(a0h, bh0, accH[0][0]);
    accH[0][1] = mma_bf16(a1h, bh0, accH[0][1]);
    accH[1][0] = mma_bf16(a0h, bh1, accH[1][0]);
    accH[1][1] = mma_bf16(a1h, bh1, accH[1][1]);
    accL[0][0] = mma_bf16(a0l, bh0, accL[0][0]);
    accL[0][1] = mma_bf16(a1l, bh0, accL[0][1]);
    accL[1][0] = mma_bf16(a0l, bh1, accL[1][0]);
    accL[1][1] = mma_bf16(a1l, bh1, accL[1][1]);
    accL[0][0] = mma_bf16(a0h, bl0, accL[0][0]);
    accL[0][1] = mma_bf16(a1h, bl0, accL[0][1]);
    accL[1][0] = mma_bf16(a0h, bl1, accL[1][0]);
    accL[1][1] = mma_bf16(a1h, bl1, accL[1][1]);
  }
}

__device__ __forceinline__ void phase_mma_reduce(
    const short* aLoH, const short* aLoL,
    const short* aHiH, const short* aHiL,
    const short* lsHi_, const short* lsLo_, float* lsRed_,
    f32x4 (&acc)[2][2], int wave, int l15, int lq) {
  const int khalf = wave >> 1, rhalf = wave & 1;
  f32x4 accH[2][2] = {}, accL[2][2] = {};
  const short* pAH = (khalf < 2) ? aLoH : aHiH;
  const short* pAL = (khalf < 2) ? aLoL : aHiL;
  mma_block(pAH, pAL, (khalf & 1) * 256, khalf * 256, lsHi_, lsLo_,
            accH, accL, l15, lq, rhalf);
#pragma unroll
  for (int ct = 0; ct < 2; ++ct)
#pragma unroll
    for (int rti = 0; rti < 2; ++rti) acc[ct][rti] = accH[ct][rti] + accL[ct][rti];
  const int pos = l15 * 16 + lq * 4;
  if (wave >= 2) {
#pragma unroll
    for (int ct = 0; ct < 2; ++ct)
#pragma unroll
      for (int rti = 0; rti < 2; ++rti)
        *(f32x4*)&lsRed_[(((wave - 2) * 2 + ct) * 2 + rti) * 256 + pos] = acc[ct][rti];
  }
  __syncthreads();
  if (wave < 2) {
#pragma unroll
    for (int s = 0; s < 3; ++s) {
      const int swi = rhalf + 2 * s;
#pragma unroll
      for (int ct = 0; ct < 2; ++ct)
#pragma unroll
        for (int rti = 0; rti < 2; ++rti)
          acc[ct][rti] += *(const f32x4*)&lsRed_[((swi * 2 + ct) * 2 + rti) * 256 + pos];
    }
  }
}

// ================= recurrence role (wg 0..95) =================
__device__ void recur_role(
    char* pool, int wg, int tid,
    const float* Wr, const float* Wz, const float* Wh,
    const float* Wrb, const float* Wzb, const float* Whb,
    const short* XeHi, const short* XeLo,
    short* X1Hi, short* X1Lo, _Float16* X1f16,
    short* h0Hi, short* h0Lo,
    short* rh0Hi, short* rh0Lo, short* rh1Hi, short* rh1Lo,
    float* z0, float* z1, float* hidOut,
    unsigned* lctr, unsigned* release, unsigned* gctr, unsigned* gmirror) {
  short* lsHi = (short*)pool;                 // 64 KB
  short* lsLo = lsHi + 32 * 1024;             // 64 KB
  float* lsRed = (float*)(pool + 131072);     // 24 KB

  const int wave = tid >> 6, lane = tid & 63, l15 = lane & 15, lq = lane >> 4;
  const bool isA = (wg < 64);
  const int layer = isA ? (wg >> 5) : ((wg - 64) >> 4);
  const int jc = isA ? (wg & 31) * 32 : ((wg - 64) & 15) * 32;
  const int grp = wg & 7;

  // ---- stage this wg's weight slice into LDS (split + swizzle), once ----
  for (int i = tid; i < 8192; i += 512) {
    const int j = i >> 8;
    const int k4 = (i & 255) << 2;
    const float* src;
    if (isA) {
      const int g = jc + j;
      src = (g < 512) ? (Wr + ((size_t)(layer * 512 + g)) * 1024 + k4)
                      : (Wz + ((size_t)(layer * 512 + g - 512)) * 1024 + k4);
    } else {
      src = Wh + ((size_t)(layer * 512 + jc + j)) * 1024 + k4;
    }
    f32x4 v = *(const f32x4*)src;
    s16x4 h4, l4;
#pragma unroll
    for (int q = 0; q < 4; ++q) { short hi, lo; split2(v[q], &hi, &lo); h4[q] = hi; l4[q] = lo; }
    const int els = (j * 1024 + k4) ^ ((j & 7) << 3);
    *(s16x4*)&lsHi[els] = h4;
    *(s16x4*)&lsLo[els] = l4;
  }
  float biasL0, biasL1;
  {
    const int j0 = jc + l15, j1 = jc + 16 + l15;
    if (isA) {
      const float* br = Wrb + layer * 512;
      const float* bz = Wzb + layer * 512;
      biasL0 = (j0 < 512) ? br[j0] : bz[j0 - 512];
      biasL1 = (j1 < 512) ? br[j1] : bz[j1 - 512];
    } else {
      const float* bh = Whb + layer * 512;
      biasL0 = bh[j0]; biasL1 = bh[j1];
    }
  }
  __syncthreads();

  for (int m = 0; m <= NT; ++m) {
    // ================= phase A: r,z gates =================
    if (isA && ((layer == 0 && m < NT) || (layer == 1 && m >= 1))) {
      const int t = (layer == 0) ? m : (m - 1);
      const short *aLoH_, *aLoL_, *aHiH_, *aHiL_;
      short *rhH_, *rhL_; float* zOut_;
      if (layer == 0) {
        aLoH_ = XeHi + (size_t)t * SZ_H; aLoL_ = XeLo + (size_t)t * SZ_H;
        aHiH_ = h0Hi + (size_t)m * SZ_H; aHiL_ = h0Lo + (size_t)m * SZ_H;
        rhH_ = rh0Hi + (size_t)t * SZ_H; rhL_ = rh0Lo + (size_t)t * SZ_H;
        zOut_ = z0 + (size_t)t * SZ_H;
      } else {
        aLoH_ = h0Hi + (size_t)m * SZ_H; aLoL_ = h0Lo + (size_t)m * SZ_H;
        aHiH_ = X1Hi + (size_t)t * SZ_H; aHiL_ = X1Lo + (size_t)t * SZ_H;
        rhH_ = rh1Hi + (size_t)t * SZ_H; rhL_ = rh1Lo + (size_t)t * SZ_H;
        zOut_ = z1 + (size_t)t * SZ_H;
      }
      f32x4 acc[2][2];
      phase_mma_reduce(aLoH_, aLoL_, aHiH_, aHiL_, lsHi, lsLo, lsRed,
                       acc, wave, l15, lq);
      if (wave < 2) {
#pragma unroll
        for (int ct = 0; ct < 2; ++ct) {
          const int j = jc + ct * 16 + l15;
          const float bv = ct ? biasL1 : biasL0;
#pragma unroll
          for (int rti = 0; rti < 2; ++rti)
#pragma unroll
            for (int r = 0; r < 4; ++r) {
              const int b = (wave * 2 + rti) * 16 + lq * 4 + r;
              const float pre = acc[ct][rti][r] + bv;
              const float s = 1.0f / (1.0f + __expf(-pre));
              if (j < 512) {
                const float hv = bf2f((unsigned short)aHiH_[b * 512 + j]) +
                                 bf2f((unsigned short)aHiL_[b * 512 + j]);
                short hi, lo; split2(s * hv, &hi, &lo);
                st_sc16(rhH_ + b * 512 + j, hi);
                st_sc16(rhL_ + b * 512 + j, lo);
              } else {
                st_sc32(zOut_ + b * 512 + (j - 512), s);
              }
            }
        }
      }
    }
    hbar(grp, 2 * m + 1, lctr, release, gctr, gmirror);

    // ================= phase B: candidate + state update =================
    if (!isA && ((layer == 0 && m < NT) || (layer == 1 && m >= 1))) {
      const int t = (layer == 0) ? m : (m - 1);
      const short *aLoH_, *aLoL_, *aHiH_, *aHiL_, *hOldH_, *hOldL_;
      short *hNewH_, *hNewL_;
      const float* zIn_;
      _Float16* xf16_ = nullptr; float* hidOut_ = nullptr;
      if (layer == 0) {
        aLoH_ = XeHi + (size_t)t * SZ_H; aLoL_ = XeLo + (size_t)t * SZ_H;
        aHiH_ = rh0Hi + (size_t)t * SZ_H; aHiL_ = rh0Lo + (size_t)t * SZ_H;
        hOldH_ = h0Hi + (size_t)m * SZ_H; hOldL_ = h0Lo + (size_t)m * SZ_H;
        hNewH_ = h0Hi + (size_t)(m + 1) * SZ_H; hNewL_ = h0Lo + (size_t)(m + 1) * SZ_H;
        zIn_ = z0 + (size_t)t * SZ_H;
        if (m == NT - 1) hidOut_ = hidOut;
      } else {
        aLoH_ = h0Hi + (size_t)m * SZ_H; aLoL_ = h0Lo + (size_t)m * SZ_H;
        aHiH_ = rh1Hi + (size_t)t * SZ_H; aHiL_ = rh1Lo + (size_t)t * SZ_H;
        hOldH_ = X1Hi + (size_t)t * SZ_H; hOldL_ = X1Lo + (size_t)t * SZ_H;
        hNewH_ = X1Hi + (size_t)(t + 1) * SZ_H; hNewL_ = X1Lo + (size_t)(t + 1) * SZ_H;
        zIn_ = z1 + (size_t)t * SZ_H;
        xf16_ = X1f16 + (size_t)t * SZ_H;
        if (m == NT) hidOut_ = hidOut + SZ_H;
      }
      f32x4 acc[2][2];
      phase_mma_reduce(aLoH_, aLoL_, aHiH_, aHiL_, lsHi, lsLo, lsRed,
                       acc, wave, l15, lq);
      if (wave < 2) {
#pragma unroll
        for (int ct = 0; ct < 2; ++ct) {
          const int j = jc + ct * 16 + l15;
          const float bv = ct ? biasL1 : biasL0;
#pragma unroll
          for (int rti = 0; rti < 2; ++rti)
#pragma unroll
            for (int r = 0; r < 4; ++r) {
              const int b = (wave * 2 + rti) * 16 + lq * 4 + r;
              const float pre = acc[ct][rti][r] + bv;
              const float hh = tanhf(pre);
              const float z = zIn_[b * 512 + j];
              const float ho = bf2f((unsigned short)hOldH_[b * 512 + j]) +
                               bf2f((unsigned short)hOldL_[b * 512 + j]);
              const float hn = (1.0f - z) * ho + z * hh;
              short hi, lo; split2(hn, &hi, &lo);
              st_sc16(hNewH_ + b * 512 + j, hi);
              st_sc16(hNewL_ + b * 512 + j, lo);
              if (xf16_) {               // consumed in-kernel by gemm wgs
                union { _Float16 f; short s; } u; u.f = (_Float16)hn;
                st_sc16((short*)&xf16_[b * 512 + j], u.s);
              }
              if (hidOut_) hidOut_[b * 512 + j] = hn;   // post-kernel consumer
            }
        }
      }
    }
    hbar(grp, 2 * m + 2, lctr, release, gctr, gmirror);
  }
}

// ================= gemm role (wg 96..223) =================
// C[4096,32000] = X1f16 @ OWf^T + bias, tiles 128x128, gated on gmirror.
__device__ void gemm_role(
    char* pool, int g, int tid,
    const _Float16* Af, const _Float16* Bw, const float* bias, float* C,
    const unsigned* gmirror) {
  _Float16* lsA = (_Float16*)pool;            // 16 KB
  _Float16* lsB = lsA + 128 * 64;             // 16 KB
  const int wave = tid >> 6, lane = tid & 63, l15 = lane & 15, lq = lane >> 4;
  const int wr = (wave >> 2) * 64, wc = (wave & 3) * 32;
  unsigned lastR = 0;

  for (int tau = g; tau < NTILE; tau += NWG_G) {
    const int bm = tau / 250, bn = tau - bm * 250;
    const unsigned Rneed = 4u * (unsigned)bm + 6u;   // X1f16[2bm+1] ready
    if (tid == 0 && lastR < Rneed) {
      unsigned v;
      do {
        __builtin_amdgcn_s_sleep(8);
        v = ld_sc32u(gmirror);
      } while (v < Rneed);
      lastR = v;
    }
    __syncthreads();

    f32x4 acc[4][2] = {};
    const size_t arow0 = (size_t)bm * 128;
    const size_t brow0 = (size_t)bn * 128;
    for (int kb = 0; kb < 512; kb += 64) {
#pragma unroll
      for (int i = 0; i < 2; ++i) {
        int c = tid + i * 512;
        int row = c >> 3, kc = (c & 7) * 8;
        f16x8 va = *(const f16x8*)(Af + (arow0 + row) * 512 + kb + kc);
        f16x8 vb = *(const f16x8*)(Bw + (brow0 + row) * 512 + kb + kc);
        int el = (row * 64 + kc) ^ ((row & 7) << 3);
        *(f16x8*)&lsA[el] = va;
        *(f16x8*)&lsB[el] = vb;
      }
      __syncthreads();
#pragma unroll
      for (int k0 = 0; k0 < 64; k0 += 32) {
        const int kk = k0 + lq * 8;
        f16x8 af[4], bfr[2];
#pragma unroll
        for (int i = 0; i < 4; ++i) {
          int ra = wr + i * 16 + l15;
          af[i] = *(const f16x8*)&lsA[(ra * 64 + kk) ^ ((ra & 7) << 3)];
        }
#pragma unroll
        for (int jt = 0; jt < 2; ++jt) {
          int rb = wc + jt * 16 + l15;
          bfr[jt] = *(const f16x8*)&lsB[(rb * 64 + kk) ^ ((rb & 7) << 3)];
        }
#pragma unroll
        for (int i = 0; i < 4; ++i)
#pragma unroll
          for (int jt = 0; jt < 2; ++jt)
            acc[i][jt] = mma_f16(af[i], bfr[jt], acc[i][jt]);
      }
      __syncthreads();
    }
#pragma unroll
    for (int i = 0; i < 4; ++i) {
#pragma unroll
      for (int jt = 0; jt < 2; ++jt) {
        const size_t col = brow0 + wc + jt * 16 + l15;
        const float bval = bias[col];
#pragma unroll
        for (int r = 0; r < 4; ++r) {
          const size_t row = arow0 + wr + i * 16 + lq * 4 + r;
          C[row * (size_t)NV + col] = acc[i][jt][r] + bval;
        }
      }
    }
  }
}

// ================= fused persistent kernel =================
__launch_bounds__(512, 1)
__global__ void k_main(
    const float* __restrict__ Wr, const float* __restrict__ Wz, const float* __restrict__ Wh,
    const float* __restrict__ Wrb, const float* __restrict__ Wzb, const float* __restrict__ Whb,
    const short* __restrict__ XeHi, const short* __restrict__ XeLo,
    short* X1Hi, short* X1Lo, _Float16* X1f16,
    short* h0Hi, short* h0Lo,
    short* rh0Hi, short* rh0Lo, short* rh1Hi, short* rh1Lo,
    float* z0, float* z1, float* hidOut,
    const _Float16* OWf, const float* outb, float* out,
    unsigned* sy) {
  __shared__ __align__(16) char pool[155648];
  const int wg = blockIdx.x;
  const int tid = threadIdx.x;
  // sync area layout (u32 indices): gctr@0, gmirror@32, lctr@64+32k, release@320+32k
  unsigned* gctr    = sy;
  unsigned* gmirror = sy + 32;
  unsigned* lctr    = sy + 64;
  unsigned* release = sy + 320;

  if (wg < NWG_R) {
    recur_role(pool, wg, tid, Wr, Wz, Wh, Wrb, Wzb, Whb, XeHi, XeLo,
               X1Hi, X1Lo, X1f16, h0Hi, h0Lo,
               rh0Hi, rh0Lo, rh1Hi, rh1Lo, z0, z1, hidOut,
               lctr, release, gctr, gmirror);
  } else {
    gemm_role(pool, wg - NWG_R, tid, X1f16, OWf, outb, out, gmirror);
  }
}

// ---------------- launcher ----------------
extern "C" void kernel_launch(void* const* d_in, const int* in_sizes, int n_in,
                              void* d_out, int out_size, void* d_ws, size_t ws_size,
                              hipStream_t stream) {
  (void)in_sizes; (void)n_in; (void)out_size; (void)ws_size;
  const int*   toks = (const int*)d_in[0];
  const float* hid  = (const float*)d_in[1];
  const float* emb  = (const float*)d_in[2];
  const float* Wr   = (const float*)d_in[3];
  const float* Wrb  = (const float*)d_in[4];
  const float* Wz   = (const float*)d_in[5];
  const float* Wzb  = (const float*)d_in[6];
  const float* Wh   = (const float*)d_in[7];
  const float* Whb  = (const float*)d_in[8];
  const float* outw = (const float*)d_in[9];
  const float* outb = (const float*)d_in[10];
  float* out = (float*)d_out;

  char* base = (char*)d_ws;
  size_t off = 0;
  auto carve = [&](size_t bytes) -> char* {
    char* r = base + off;
    off = (off + bytes + 255) & ~(size_t)255;
    return r;
  };
  _Float16* OWf   = (_Float16*)carve(SZ_OW * 2);
  short*    XeHi  = (short*)carve(SZ_XE * 2);
  short*    XeLo  = (short*)carve(SZ_XE * 2);
  // per-timestep versioned cross-wg buffers (never reuse an address)
  short*    X1Hi  = (short*)carve((size_t)(NT + 1) * SZ_H * 2);
  short*    X1Lo  = (short*)carve((size_t)(NT + 1) * SZ_H * 2);
  _Float16* X1f16 = (_Float16*)carve((size_t)NT * SZ_H * 2);
  short*    h0Hi  = (short*)carve((size_t)(NT + 1) * SZ_H * 2);
  short*    h0Lo  = (short*)carve((size_t)(NT + 1) * SZ_H * 2);
  short*    rh0Hi = (short*)carve((size_t)NT * SZ_H * 2);
  short*    rh0Lo = (short*)carve((size_t)NT * SZ_H * 2);
  short*    rh1Hi = (short*)carve((size_t)NT * SZ_H * 2);
  short*    rh1Lo = (short*)carve((size_t)NT * SZ_H * 2);
  float*    z0    = (float*)carve((size_t)NT * SZ_H * 4);
  float*    z1    = (float*)carve((size_t)NT * SZ_H * 4);
  unsigned* sy    = (unsigned*)carve(4096);

  hipMemsetAsync(sy, 0, 4096, stream);

  k_prep<<<2048, 256, 0, stream>>>(outw, toks, emb, hid,
                                   OWf, XeHi, XeLo, X1Hi, X1Lo, h0Hi, h0Lo);

  k_main<<<NWG_R + NWG_G, 512, 0, stream>>>(
      Wr, Wz, Wh, Wrb, Wzb, Whb, XeHi, XeLo,
      X1Hi, X1Lo, X1f16, h0Hi, h0Lo,
      rh0Hi, rh0Lo, rh1Hi, rh1Lo, z0, z1,
      out + LOGITS, OWf, outb, out, sy);
}

// Round 5
// 1173.025 us; speedup vs baseline: 4.0357x; 1.8336x over previous
//
#include <hip/hip_runtime.h>

// ---------------- constants ----------------
constexpr int NT = 64;     // timesteps
constexpr int NB = 64;     // batch
constexpr int NV = 32000;  // vocab
constexpr int NE = 512;    // embed
constexpr int NH = 512;    // hidden
constexpr int NWG_A = 128; // gate-phase wgs: 2 layers x 32 colgroups x 2 rowhalves
constexpr int NWG_R = 192; // + 64 B-wgs (2 layers x 16 cg x 2 rowhalves)
constexpr int NWG_G = 64;  // gemm consumer wgs  (total 256 = all CUs)
constexpr int NTILE = 32 * 250;

constexpr size_t SZ_OW  = (size_t)NV * NE;
constexpr size_t SZ_XE  = (size_t)NT * NB * NE;
constexpr size_t SZ_H   = (size_t)NB * NH;
constexpr size_t LOGITS = (size_t)NT * NB * NV;

typedef float f32x4 __attribute__((ext_vector_type(4)));
typedef int   i32x4 __attribute__((ext_vector_type(4)));
typedef short bf16x8 __attribute__((ext_vector_type(8)));
typedef short s16x4 __attribute__((ext_vector_type(4)));
typedef _Float16 f16x8 __attribute__((ext_vector_type(8)));

// ---------------- helpers ----------------
__device__ __forceinline__ unsigned short f2bf(float x) {
  unsigned u = __float_as_uint(x);
  u += 0x7FFFu + ((u >> 16) & 1u);            // RNE
  return (unsigned short)(u >> 16);
}
__device__ __forceinline__ float bf2f(unsigned short s) {
  return __uint_as_float(((unsigned)s) << 16);
}
__device__ __forceinline__ void split2(float v, short* hi, short* lo) {
  unsigned short h = f2bf(v);
  *hi = (short)h;
  *lo = (short)f2bf(v - bf2f(h));
}
__device__ __forceinline__ f32x4 mma_bf16(bf16x8 a, bf16x8 b, f32x4 c) {
  return __builtin_amdgcn_mfma_f32_16x16x32_bf16(a, b, c, 0, 0, 0);
}
__device__ __forceinline__ f32x4 mma_f16(f16x8 a, f16x8 b, f32x4 c) {
  return __builtin_amdgcn_mfma_f32_16x16x32_f16(a, b, c, 0, 0, 0);
}

// write-through-to-LLC stores (LLC/MALL = chip-level coherence point)
__device__ __forceinline__ void st_sc32u(unsigned* p, unsigned v) {
  asm volatile("global_store_dword %0, %1, off sc0 sc1" :: "v"(p), "v"(v) : "memory");
}
__device__ __forceinline__ void st_sc128(void* p, i32x4 v) {
  asm volatile("global_store_dwordx4 %0, %1, off sc0 sc1" :: "v"(p), "v"(v) : "memory");
}
// fresh MALL read, NON-atomic
__device__ __forceinline__ unsigned ld_sc32u(const unsigned* p) {
  unsigned v;
  asm volatile("global_load_dword %0, %1, off sc0 sc1\n\ts_waitcnt vmcnt(0)"
               : "=v"(v) : "v"(p) : "memory");
  return v;
}

// Broadcast flag barrier: arrival = 1 sc store to own flag; detection =
// parallel per-lane poll of all 192 flags (waves 0..2), divergent spin.
__device__ __forceinline__ void fbar(int wg, unsigned r, unsigned* flags) {
  asm volatile("s_waitcnt vmcnt(0)" ::: "memory");  // data stores drained
  __syncthreads();
  const int tid = threadIdx.x;
  if (tid == 0) st_sc32u(&flags[(size_t)wg * 32], r);
  const int wv = tid >> 6, ln = tid & 63;
  if (wv < 3) {
    const unsigned* fp = &flags[(size_t)(wv * 64 + ln) * 32];
    while (ld_sc32u(fp) < r) __builtin_amdgcn_s_sleep(2);
  }
  __syncthreads();
}

// ---------------- prep ----------------
__global__ void k_prep(
    const float* __restrict__ outw, const int* __restrict__ toks,
    const float* __restrict__ emb, const float* __restrict__ hid,
    _Float16* OWf, short* XeHi, short* XeLo,
    short* X1Hi, short* X1Lo, short* h0Hi, short* h0Lo) {
  const size_t stride = (size_t)gridDim.x * blockDim.x;
  const size_t N1 = SZ_OW, N2 = N1 + SZ_XE, N3 = N2 + SZ_H, N4 = N3 + SZ_H;
  for (size_t x = (size_t)blockIdx.x * blockDim.x + threadIdx.x; x < N4; x += stride) {
    if (x < N1) {
      OWf[x] = (_Float16)outw[x];
    } else if (x < N2) {
      size_t p = x - N1;
      size_t r = p >> 9, c = p & 511u;
      int tok = toks[r];
      float v = emb[(size_t)tok * 512 + c];
      short hi, lo; split2(v, &hi, &lo);
      XeHi[p] = hi; XeLo[p] = lo;
    } else if (x < N3) {
      size_t p = x - N2;
      short hi, lo; split2(hid[p], &hi, &lo);
      h0Hi[p] = hi; h0Lo[p] = lo;
    } else {
      size_t p = x - N3;
      short hi, lo; split2(hid[SZ_H + p], &hi, &lo);
      X1Hi[p] = hi; X1Lo[p] = lo;
    }
  }
}

// ---------------- recurrence MMA core (one 16-row tile per wave) ----------------
__device__ __forceinline__ void mma_block32(
    const short* __restrict__ pAH, const short* __restrict__ pAL,
    int kloc0, int kkGlob0,
    const short* lsHi_, const short* lsLo_,
    f32x4 (&accH)[2], f32x4 (&accL)[2],
    int l15, int lq, int rhalf, int rowbase) {
  const int r0 = rowbase + rhalf * 16 + l15;
#pragma unroll 4
  for (int i = 0; i < 8; ++i) {
    const int kk = kkGlob0 + i * 32 + lq * 8;
    const int ka = kloc0 + i * 32 + lq * 8;
    const int e0 = (l15 * 1024 + kk) ^ ((l15 & 7) << 3);
    const int e1 = ((16 + l15) * 1024 + kk) ^ ((l15 & 7) << 3);
    bf16x8 bh0 = *(const bf16x8*)&lsHi_[e0];
    bf16x8 bl0 = *(const bf16x8*)&lsLo_[e0];
    bf16x8 bh1 = *(const bf16x8*)&lsHi_[e1];
    bf16x8 bl1 = *(const bf16x8*)&lsLo_[e1];
    bf16x8 ah = *(const bf16x8*)&pAH[r0 * 512 + ka];
    bf16x8 al = *(const bf16x8*)&pAL[r0 * 512 + ka];
    accH[0] = mma_bf16(ah, bh0, accH[0]);
    accH[1] = mma_bf16(ah, bh1, accH[1]);
    accL[0] = mma_bf16(al, bh0, accL[0]);
    accL[1] = mma_bf16(al, bh1, accL[1]);
    accL[0] = mma_bf16(ah, bl0, accL[0]);
    accL[1] = mma_bf16(ah, bl1, accL[1]);
  }
}

// MMA + cross-wave k-reduce. Returns final sums in waves 0,1 (wave=rhalf).
__device__ __forceinline__ void phase_mma_reduce(
    const short* aLoH, const short* aLoL,
    const short* aHiH, const short* aHiL,
    const short* lsHi_, const short* lsLo_, float* lsRed_,
    f32x4 (&acc)[2], int wave, int l15, int lq, int rowbase) {
  const int khalf = wave >> 1, rhalf = wave & 1;
  f32x4 accH[2] = {}, accL[2] = {};
  const short* pAH = (khalf < 2) ? aLoH : aHiH;
  const short* pAL = (khalf < 2) ? aLoL : aHiL;
  mma_block32(pAH, pAL, (khalf & 1) * 256, khalf * 256, lsHi_, lsLo_,
              accH, accL, l15, lq, rhalf, rowbase);
  acc[0] = accH[0] + accL[0];
  acc[1] = accH[1] + accL[1];
  const int pos = l15 * 16 + lq * 4;
  if (wave >= 2) {
    *(f32x4*)&lsRed_[((wave - 2) * 2 + 0) * 256 + pos] = acc[0];
    *(f32x4*)&lsRed_[((wave - 2) * 2 + 1) * 256 + pos] = acc[1];
  }
  __syncthreads();
  if (wave < 2) {
#pragma unroll
    for (int s = 0; s < 3; ++s) {
      const int slot = (wave & 1) + 2 * s;
      acc[0] += *(const f32x4*)&lsRed_[(slot * 2 + 0) * 256 + pos];
      acc[1] += *(const f32x4*)&lsRed_[(slot * 2 + 1) * 256 + pos];
    }
  }
  __syncthreads();   // lsRed free for reuse as epilogue scratch
}

// ================= recurrence role (wg 0..191) =================
__device__ void recur_role(
    char* pool, int wg, int tid,
    const float* Wr, const float* Wz, const float* Wh,
    const float* Wrb, const float* Wzb, const float* Whb,
    const short* XeHi, const short* XeLo,
    short* X1Hi, short* X1Lo, _Float16* X1f16,
    short* h0Hi, short* h0Lo,
    short* rh0Hi, short* rh0Lo, short* rh1Hi, short* rh1Lo,
    float* z0, float* z1, float* hidOut, unsigned* flags) {
  short* lsHi = (short*)pool;                 // 64 KB weight hi
  short* lsLo = lsHi + 32 * 1024;             // 64 KB weight lo
  float* lsRed = (float*)(pool + 131072);     // 12 KB partials / epilogue scratch
  short* stH  = (short*)(pool + 143360);      // 2 KB hOld hi stage
  short* stL  = stH + 1024;                   // 2 KB hOld lo stage
  float* stZ  = (float*)(pool + 147456);      // 4 KB z stage

  const int wave = tid >> 6, lane = tid & 63, l15 = lane & 15, lq = lane >> 4;
  const bool isA = (wg < NWG_A);
  int layer, cg, rh01;
  if (isA) { layer = wg >> 6; cg = (wg >> 1) & 31; rh01 = wg & 1; }
  else { int b = wg - NWG_A; layer = b >> 5; cg = (b >> 1) & 15; rh01 = b & 1; }
  const int jc = cg * 32;
  const int rowbase = rh01 * 32;

  // ---- stage this wg's 32-row weight slice into LDS (split + swizzle) ----
  for (int i = tid; i < 8192; i += 512) {
    const int j = i >> 8;
    const int k4 = (i & 255) << 2;
    const float* src;
    if (isA) {
      const int g = jc + j;
      src = (g < 512) ? (Wr + ((size_t)(layer * 512 + g)) * 1024 + k4)
                      : (Wz + ((size_t)(layer * 512 + g - 512)) * 1024 + k4);
    } else {
      src = Wh + ((size_t)(layer * 512 + jc + j)) * 1024 + k4;
    }
    f32x4 v = *(const f32x4*)src;
    s16x4 h4, l4;
#pragma unroll
    for (int q = 0; q < 4; ++q) { short hi, lo; split2(v[q], &hi, &lo); h4[q] = hi; l4[q] = lo; }
    const int els = (j * 1024 + k4) ^ ((j & 7) << 3);
    *(s16x4*)&lsHi[els] = h4;
    *(s16x4*)&lsLo[els] = l4;
  }
  float biasL0, biasL1;
  {
    const int j0 = jc + l15, j1 = jc + 16 + l15;
    if (isA) {
      const float* br = Wrb + layer * 512;
      const float* bz = Wzb + layer * 512;
      biasL0 = (j0 < 512) ? br[j0] : bz[j0 - 512];
      biasL1 = (j1 < 512) ? br[j1] : bz[j1 - 512];
    } else {
      const float* bh = Whb + layer * 512;
      biasL0 = bh[j0]; biasL1 = bh[j1];
    }
  }
  __syncthreads();

  for (int m = 0; m <= NT; ++m) {
    // ================= phase A: r,z gates =================
    if (isA && ((layer == 0 && m < NT) || (layer == 1 && m >= 1))) {
      const int t = (layer == 0) ? m : (m - 1);
      const short *aLoH_, *aLoL_, *aHiH_, *aHiL_;
      short *rhH_, *rhL_; float* zOut_;
      if (layer == 0) {
        aLoH_ = XeHi + (size_t)t * SZ_H; aLoL_ = XeLo + (size_t)t * SZ_H;
        aHiH_ = h0Hi + (size_t)m * SZ_H; aHiL_ = h0Lo + (size_t)m * SZ_H;
        rhH_ = rh0Hi + (size_t)t * SZ_H; rhL_ = rh0Lo + (size_t)t * SZ_H;
        zOut_ = z0 + (size_t)t * SZ_H;
      } else {
        aLoH_ = h0Hi + (size_t)m * SZ_H; aLoL_ = h0Lo + (size_t)m * SZ_H;
        aHiH_ = X1Hi + (size_t)t * SZ_H; aHiL_ = X1Lo + (size_t)t * SZ_H;
        rhH_ = rh1Hi + (size_t)t * SZ_H; rhL_ = rh1Lo + (size_t)t * SZ_H;
        zOut_ = z1 + (size_t)t * SZ_H;
      }
      f32x4 acc[2];
      phase_mma_reduce(aLoH_, aLoL_, aHiH_, aHiL_, lsHi, lsLo, lsRed,
                       acc, wave, l15, lq, rowbase);
      const bool isR = (jc < 512);
      short* sH = (short*)lsRed;
      short* sL = sH + 1024;
      float* sZ = lsRed;
      if (wave < 2) {
#pragma unroll
        for (int ct = 0; ct < 2; ++ct) {
          const int jj = ct * 16 + l15;
          const int j = jc + jj;
          const float bv = ct ? biasL1 : biasL0;
#pragma unroll
          for (int r = 0; r < 4; ++r) {
            const int lb = wave * 16 + lq * 4 + r;
            const int b = rowbase + lb;
            const float pre = acc[ct][r] + bv;
            const float s = 1.0f / (1.0f + __expf(-pre));
            if (isR) {
              const float hv = bf2f((unsigned short)aHiH_[b * 512 + j]) +
                               bf2f((unsigned short)aHiL_[b * 512 + j]);
              short hi, lo; split2(s * hv, &hi, &lo);
              sH[lb * 32 + jj] = hi; sL[lb * 32 + jj] = lo;
            } else {
              sZ[lb * 32 + jj] = s;
            }
          }
        }
      }
      __syncthreads();
      if (isR) {
        if (tid < 256) {
          const int buf = tid >> 7, lb = (tid & 127) >> 2, c = tid & 3;
          i32x4 v = *(const i32x4*)&(buf ? sL : sH)[lb * 32 + c * 8];
          st_sc128((buf ? rhL_ : rhH_) + (size_t)(rowbase + lb) * 512 + jc + c * 8, v);
        }
      } else {
        if (tid < 256) {
          const int lb = tid >> 3, c = tid & 7;
          i32x4 v = *(const i32x4*)&sZ[lb * 32 + c * 4];
          st_sc128(zOut_ + (size_t)(rowbase + lb) * 512 + (jc - 512) + c * 4, v);
        }
      }
    }
    fbar(wg, 2u * m + 1u, flags);

    // ================= phase B: candidate + state update =================
    if (!isA && ((layer == 0 && m < NT) || (layer == 1 && m >= 1))) {
      const int t = (layer == 0) ? m : (m - 1);
      const short *aLoH_, *aLoL_, *aHiH_, *aHiL_, *hOldH_, *hOldL_;
      short *hNewH_, *hNewL_;
      const float* zIn_;
      _Float16* xf16_ = nullptr; float* hidOut_ = nullptr;
      if (layer == 0) {
        aLoH_ = XeHi + (size_t)t * SZ_H; aLoL_ = XeLo + (size_t)t * SZ_H;
        aHiH_ = rh0Hi + (size_t)t * SZ_H; aHiL_ = rh0Lo + (size_t)t * SZ_H;
        hOldH_ = h0Hi + (size_t)m * SZ_H; hOldL_ = h0Lo + (size_t)m * SZ_H;
        hNewH_ = h0Hi + (size_t)(m + 1) * SZ_H; hNewL_ = h0Lo + (size_t)(m + 1) * SZ_H;
        zIn_ = z0 + (size_t)t * SZ_H;
        if (m == NT - 1) hidOut_ = hidOut;
      } else {
        aLoH_ = h0Hi + (size_t)m * SZ_H; aLoL_ = h0Lo + (size_t)m * SZ_H;
        aHiH_ = rh1Hi + (size_t)t * SZ_H; aHiL_ = rh1Lo + (size_t)t * SZ_H;
        hOldH_ = X1Hi + (size_t)t * SZ_H; hOldL_ = X1Lo + (size_t)t * SZ_H;
        hNewH_ = X1Hi + (size_t)(t + 1) * SZ_H; hNewL_ = X1Lo + (size_t)(t + 1) * SZ_H;
        zIn_ = z1 + (size_t)t * SZ_H;
        xf16_ = X1f16 + (size_t)t * SZ_H;
        if (m == NT) hidOut_ = hidOut + SZ_H;
      }
      // prestage hOld and z (coalesced plain loads -> LDS) before the MMA
      if (tid < 256) {
        const int buf = tid >> 7, lb = (tid & 127) >> 2, c = tid & 3;
        const short* src = (buf ? hOldL_ : hOldH_) + (size_t)(rowbase + lb) * 512 + jc + c * 8;
        *(i32x4*)&(buf ? stL : stH)[lb * 32 + c * 8] = *(const i32x4*)src;
      } else {
        const int q = tid - 256, lb = q >> 3, c = q & 7;
        *(f32x4*)&stZ[lb * 32 + c * 4] =
            *(const f32x4*)(zIn_ + (size_t)(rowbase + lb) * 512 + jc + c * 4);
      }
      f32x4 acc[2];
      phase_mma_reduce(aLoH_, aLoL_, aHiH_, aHiL_, lsHi, lsLo, lsRed,
                       acc, wave, l15, lq, rowbase);
      short* sH = (short*)lsRed;
      short* sL = sH + 1024;
      _Float16* sX = (_Float16*)(sL + 1024);
      if (wave < 2) {
#pragma unroll
        for (int ct = 0; ct < 2; ++ct) {
          const int jj = ct * 16 + l15;
          const int j = jc + jj;
          const float bv = ct ? biasL1 : biasL0;
#pragma unroll
          for (int r = 0; r < 4; ++r) {
            const int lb = wave * 16 + lq * 4 + r;
            const int b = rowbase + lb;
            const float pre = acc[ct][r] + bv;
            const float hh = tanhf(pre);
            const float z = stZ[lb * 32 + jj];
            const float ho = bf2f((unsigned short)stH[lb * 32 + jj]) +
                             bf2f((unsigned short)stL[lb * 32 + jj]);
            const float hn = (1.0f - z) * ho + z * hh;
            short hi, lo; split2(hn, &hi, &lo);
            sH[lb * 32 + jj] = hi; sL[lb * 32 + jj] = lo;
            if (layer == 1) sX[lb * 32 + jj] = (_Float16)hn;
            if (hidOut_) hidOut_[b * 512 + j] = hn;   // rare (final step), plain
          }
        }
      }
      __syncthreads();
      if (tid < 256) {
        const int buf = tid >> 7, lb = (tid & 127) >> 2, c = tid & 3;
        i32x4 v = *(const i32x4*)&(buf ? sL : sH)[lb * 32 + c * 8];
        st_sc128((buf ? hNewL_ : hNewH_) + (size_t)(rowbase + lb) * 512 + jc + c * 8, v);
      } else if (layer == 1 && tid < 384) {
        const int q = tid - 256, lb = q >> 2, c = q & 3;
        i32x4 v = *(const i32x4*)&sX[lb * 32 + c * 8];
        st_sc128(xf16_ + (size_t)(rowbase + lb) * 512 + jc + c * 8, v);
      }
    }
    fbar(wg, 2u * m + 2u, flags);
  }
}

// ================= gemm role (wg 192..255) =================
__device__ void gemm_role(
    char* pool, int g, int tid,
    const _Float16* Af, const _Float16* Bw, const float* bias, float* C,
    unsigned* flags) {
  _Float16* lsA = (_Float16*)pool;
  _Float16* lsB = lsA + 128 * 64;
  const int wave = tid >> 6, lane = tid & 63, l15 = lane & 15, lq = lane >> 4;
  const int wr = (wave >> 2) * 64, wc = (wave & 3) * 32;
  unsigned lastR = 0;

  for (int tau = g; tau < NTILE; tau += NWG_G) {
    const int bm = tau / 250, bn = tau - bm * 250;
    const unsigned Rneed = 4u * (unsigned)bm + 6u;   // X1f16[2bm+1] ready
    if (lastR < Rneed) {
      const int ln = tid & 63;
      if (tid < 32) {  // poll the 32 layer-1 B-wg flags (wgs 160..191)
        const unsigned* fp = &flags[(size_t)(160 + ln) * 32];
        while (ld_sc32u(fp) < Rneed) __builtin_amdgcn_s_sleep(8);
      }
      lastR = Rneed;
    }
    __syncthreads();

    f32x4 acc[4][2] = {};
    const size_t arow0 = (size_t)bm * 128;
    const size_t brow0 = (size_t)bn * 128;
    for (int kb = 0; kb < 512; kb += 64) {
#pragma unroll
      for (int i = 0; i < 2; ++i) {
        int c = tid + i * 512;
        int row = c >> 3, kc = (c & 7) * 8;
        f16x8 va = *(const f16x8*)(Af + (arow0 + row) * 512 + kb + kc);
        f16x8 vb = *(const f16x8*)(Bw + (brow0 + row) * 512 + kb + kc);
        int el = (row * 64 + kc) ^ ((row & 7) << 3);
        *(f16x8*)&lsA[el] = va;
        *(f16x8*)&lsB[el] = vb;
      }
      __syncthreads();
#pragma unroll
      for (int k0 = 0; k0 < 64; k0 += 32) {
        const int kk = k0 + lq * 8;
        f16x8 af[4], bfr[2];
#pragma unroll
        for (int i = 0; i < 4; ++i) {
          int ra = wr + i * 16 + l15;
          af[i] = *(const f16x8*)&lsA[(ra * 64 + kk) ^ ((ra & 7) << 3)];
        }
#pragma unroll
        for (int jt = 0; jt < 2; ++jt) {
          int rb = wc + jt * 16 + l15;
          bfr[jt] = *(const f16x8*)&lsB[(rb * 64 + kk) ^ ((rb & 7) << 3)];
        }
#pragma unroll
        for (int i = 0; i < 4; ++i)
#pragma unroll
          for (int jt = 0; jt < 2; ++jt)
            acc[i][jt] = mma_f16(af[i], bfr[jt], acc[i][jt]);
      }
      __syncthreads();
    }
#pragma unroll
    for (int i = 0; i < 4; ++i) {
#pragma unroll
      for (int jt = 0; jt < 2; ++jt) {
        const size_t col = brow0 + wc + jt * 16 + l15;
        const float bval = bias[col];
#pragma unroll
        for (int r = 0; r < 4; ++r) {
          const size_t row = arow0 + wr + i * 16 + lq * 4 + r;
          C[row * (size_t)NV + col] = acc[i][jt][r] + bval;
        }
      }
    }
  }
}

// ================= fused persistent kernel =================
__launch_bounds__(512, 1)
__global__ void k_main(
    const float* __restrict__ Wr, const float* __restrict__ Wz, const float* __restrict__ Wh,
    const float* __restrict__ Wrb, const float* __restrict__ Wzb, const float* __restrict__ Whb,
    const short* __restrict__ XeHi, const short* __restrict__ XeLo,
    short* X1Hi, short* X1Lo, _Float16* X1f16,
    short* h0Hi, short* h0Lo,
    short* rh0Hi, short* rh0Lo, short* rh1Hi, short* rh1Lo,
    float* z0, float* z1, float* hidOut,
    const _Float16* OWf, const float* outb, float* out,
    unsigned* flags) {
  __shared__ __align__(16) char pool[151552];
  const int wg = blockIdx.x;
  const int tid = threadIdx.x;
  if (wg < NWG_R) {
    recur_role(pool, wg, tid, Wr, Wz, Wh, Wrb, Wzb, Whb, XeHi, XeLo,
               X1Hi, X1Lo, X1f16, h0Hi, h0Lo,
               rh0Hi, rh0Lo, rh1Hi, rh1Lo, z0, z1, hidOut, flags);
  } else {
    gemm_role(pool, wg - NWG_R, tid, X1f16, OWf, outb, out, flags);
  }
}

// ---------------- launcher ----------------
extern "C" void kernel_launch(void* const* d_in, const int* in_sizes, int n_in,
                              void* d_out, int out_size, void* d_ws, size_t ws_size,
                              hipStream_t stream) {
  (void)in_sizes; (void)n_in; (void)out_size; (void)ws_size;
  const int*   toks = (const int*)d_in[0];
  const float* hid  = (const float*)d_in[1];
  const float* emb  = (const float*)d_in[2];
  const float* Wr   = (const float*)d_in[3];
  const float* Wrb  = (const float*)d_in[4];
  const float* Wz   = (const float*)d_in[5];
  const float* Wzb  = (const float*)d_in[6];
  const float* Wh   = (const float*)d_in[7];
  const float* Whb  = (const float*)d_in[8];
  const float* outw = (const float*)d_in[9];
  const float* outb = (const float*)d_in[10];
  float* out = (float*)d_out;

  char* base = (char*)d_ws;
  size_t off = 0;
  auto carve = [&](size_t bytes) -> char* {
    char* r = base + off;
    off = (off + bytes + 255) & ~(size_t)255;
    return r;
  };
  _Float16* OWf   = (_Float16*)carve(SZ_OW * 2);
  short*    XeHi  = (short*)carve(SZ_XE * 2);
  short*    XeLo  = (short*)carve(SZ_XE * 2);
  short*    X1Hi  = (short*)carve((size_t)(NT + 1) * SZ_H * 2);
  short*    X1Lo  = (short*)carve((size_t)(NT + 1) * SZ_H * 2);
  _Float16* X1f16 = (_Float16*)carve((size_t)NT * SZ_H * 2);
  short*    h0Hi  = (short*)carve((size_t)(NT + 1) * SZ_H * 2);
  short*    h0Lo  = (short*)carve((size_t)(NT + 1) * SZ_H * 2);
  short*    rh0Hi = (short*)carve((size_t)NT * SZ_H * 2);
  short*    rh0Lo = (short*)carve((size_t)NT * SZ_H * 2);
  short*    rh1Hi = (short*)carve((size_t)NT * SZ_H * 2);
  short*    rh1Lo = (short*)carve((size_t)NT * SZ_H * 2);
  float*    z0    = (float*)carve((size_t)NT * SZ_H * 4);
  float*    z1    = (float*)carve((size_t)NT * SZ_H * 4);
  unsigned* flags = (unsigned*)carve(32768);

  hipMemsetAsync(flags, 0, 32768, stream);

  k_prep<<<2048, 256, 0, stream>>>(outw, toks, emb, hid,
                                   OWf, XeHi, XeLo, X1Hi, X1Lo, h0Hi, h0Lo);

  k_main<<<NWG_R + NWG_G, 512, 0, stream>>>(
      Wr, Wz, Wh, Wrb, Wzb, Whb, XeHi, XeLo,
      X1Hi, X1Lo, X1f16, h0Hi, h0Lo,
      rh0Hi, rh0Lo, rh1Hi, rh1Lo, z0, z1,
      out + LOGITS, OWf, outb, out, flags);
}

// Round 6
// 946.137 us; speedup vs baseline: 5.0035x; 1.2398x over previous
//
#include <hip/hip_runtime.h>

// ---------------- constants ----------------
constexpr int NT = 64;     // timesteps
constexpr int NB = 64;     // batch
constexpr int NV = 32000;  // vocab
constexpr int NE = 512;    // embed
constexpr int NH = 512;    // hidden
// recurrence wg classes: [0,32) l0A | [32,96) l1A | [96,112) l0B | [112,128) l1B
constexpr int NWG_R = 128;
constexpr int NWG_G = 128; // gemm wgs -> total 256 = all CUs
constexpr int NTILE = 32 * 250;

constexpr size_t SZ_OW  = (size_t)NV * NE;
constexpr size_t SZ_XE  = (size_t)NT * NB * NE;
constexpr size_t SZ_H   = (size_t)NB * NH;
constexpr size_t LOGITS = (size_t)NT * NB * NV;

typedef float f32x4 __attribute__((ext_vector_type(4)));
typedef int   i32x4 __attribute__((ext_vector_type(4)));
typedef short bf16x8 __attribute__((ext_vector_type(8)));
typedef short s16x4 __attribute__((ext_vector_type(4)));
typedef _Float16 f16x8 __attribute__((ext_vector_type(8)));

// ---------------- helpers ----------------
__device__ __forceinline__ unsigned short f2bf(float x) {
  unsigned u = __float_as_uint(x);
  u += 0x7FFFu + ((u >> 16) & 1u);            // RNE
  return (unsigned short)(u >> 16);
}
__device__ __forceinline__ float bf2f(unsigned short s) {
  return __uint_as_float(((unsigned)s) << 16);
}
__device__ __forceinline__ void split2(float v, short* hi, short* lo) {
  unsigned short h = f2bf(v);
  *hi = (short)h;
  *lo = (short)f2bf(v - bf2f(h));
}
__device__ __forceinline__ f32x4 mma_bf16(bf16x8 a, bf16x8 b, f32x4 c) {
  return __builtin_amdgcn_mfma_f32_16x16x32_bf16(a, b, c, 0, 0, 0);
}
__device__ __forceinline__ f32x4 mma_f16(f16x8 a, f16x8 b, f32x4 c) {
  return __builtin_amdgcn_mfma_f32_16x16x32_f16(a, b, c, 0, 0, 0);
}

// write-through-to-LLC stores (LLC/MALL = chip-level coherence point)
__device__ __forceinline__ void st_sc32u(unsigned* p, unsigned v) {
  asm volatile("global_store_dword %0, %1, off sc0 sc1" :: "v"(p), "v"(v) : "memory");
}
__device__ __forceinline__ void st_sc128(void* p, i32x4 v) {
  asm volatile("global_store_dwordx4 %0, %1, off sc0 sc1" :: "v"(p), "v"(v) : "memory");
}
// fresh MALL read, NON-atomic
__device__ __forceinline__ unsigned ld_sc32u(const unsigned* p) {
  unsigned v;
  asm volatile("global_load_dword %0, %1, off sc0 sc1\n\ts_waitcnt vmcnt(0)"
               : "=v"(v) : "v"(p) : "memory");
  return v;
}

// Wait on flags[base..base+n) >= thr (n <= 64; lanes of wave 0 poll in parallel).
__device__ __forceinline__ void wait_flags(const unsigned* flags, int base, int n,
                                           unsigned thr) {
  const int tid = threadIdx.x;
  if (tid < n) {
    const unsigned* fp = &flags[(size_t)(base + tid) * 32];
    while (ld_sc32u(fp) < thr) __builtin_amdgcn_s_sleep(1);
  }
  __syncthreads();
}
// Publish own flag after draining this wg's data stores.
__device__ __forceinline__ void publish(unsigned* flags, int slot, unsigned val) {
  asm volatile("s_waitcnt vmcnt(0)" ::: "memory");
  __syncthreads();
  if (threadIdx.x == 0) st_sc32u(&flags[(size_t)slot * 32], val);
}

// ---------------- prep ----------------
__global__ void k_prep(
    const float* __restrict__ outw, const int* __restrict__ toks,
    const float* __restrict__ emb, const float* __restrict__ hid,
    _Float16* OWf, short* XeHi, short* XeLo,
    short* X1Hi, short* X1Lo, short* h0Hi, short* h0Lo) {
  const size_t stride = (size_t)gridDim.x * blockDim.x;
  const size_t N1 = SZ_OW, N2 = N1 + SZ_XE, N3 = N2 + SZ_H, N4 = N3 + SZ_H;
  for (size_t x = (size_t)blockIdx.x * blockDim.x + threadIdx.x; x < N4; x += stride) {
    if (x < N1) {
      OWf[x] = (_Float16)outw[x];
    } else if (x < N2) {
      size_t p = x - N1;
      size_t r = p >> 9, c = p & 511u;
      int tok = toks[r];
      float v = emb[(size_t)tok * 512 + c];
      short hi, lo; split2(v, &hi, &lo);
      XeHi[p] = hi; XeLo[p] = lo;
    } else if (x < N3) {
      size_t p = x - N2;
      short hi, lo; split2(hid[p], &hi, &lo);
      h0Hi[p] = hi; h0Lo[p] = lo;
    } else {
      size_t p = x - N3;
      short hi, lo; split2(hid[SZ_H + p], &hi, &lo);
      X1Hi[p] = hi; X1Lo[p] = lo;
    }
  }
}

// ---------------- P-class MMA: one 512-k half, 64 rows, 32 cols ----------------
// wave = rq(0..3)*2 + ks(0..1); acc persists across halves (register-carried).
__device__ __forceinline__ void mmaP(
    const short* __restrict__ aH, const short* __restrict__ aL, int base,
    const short* lsHi_, const short* lsLo_,
    f32x4 (&accH)[2], f32x4 (&accL)[2], int wave, int l15, int lq) {
  const int rq = wave >> 1, ks = wave & 1;
  const int r0 = rq * 16 + l15;
#pragma unroll 4
  for (int i = 0; i < 8; ++i) {
    const int ko = ks * 256 + i * 32 + lq * 8;   // offset within this half
    const int kg = base + ko;                    // global k (weight LDS index)
    const int e0 = (l15 * 1024 + kg) ^ ((l15 & 7) << 3);
    const int e1 = ((16 + l15) * 1024 + kg) ^ ((l15 & 7) << 3);
    bf16x8 bh0 = *(const bf16x8*)&lsHi_[e0];
    bf16x8 bl0 = *(const bf16x8*)&lsLo_[e0];
    bf16x8 bh1 = *(const bf16x8*)&lsHi_[e1];
    bf16x8 bl1 = *(const bf16x8*)&lsLo_[e1];
    bf16x8 ah = *(const bf16x8*)&aH[r0 * 512 + ko];
    bf16x8 al = *(const bf16x8*)&aL[r0 * 512 + ko];
    accH[0] = mma_bf16(ah, bh0, accH[0]);
    accH[1] = mma_bf16(ah, bh1, accH[1]);
    accL[0] = mma_bf16(al, bh0, accL[0]);
    accL[1] = mma_bf16(al, bh1, accL[1]);
    accL[0] = mma_bf16(ah, bl0, accL[0]);
    accL[1] = mma_bf16(ah, bl1, accL[1]);
  }
}
// pair-reduce: ks=1 waves donate partials; ks=0 waves own final acc.
__device__ __forceinline__ void reduceP(float* lsRed_, f32x4 (&accH)[2], f32x4 (&accL)[2],
                                        f32x4 (&acc)[2], int wave, int l15, int lq) {
  const int rq = wave >> 1, ks = wave & 1;
  acc[0] = accH[0] + accL[0];
  acc[1] = accH[1] + accL[1];
  const int pos = l15 * 16 + lq * 4;
  if (ks) {
    *(f32x4*)&lsRed_[(rq * 2 + 0) * 256 + pos] = acc[0];
    *(f32x4*)&lsRed_[(rq * 2 + 1) * 256 + pos] = acc[1];
  }
  __syncthreads();
  if (!ks) {
    acc[0] += *(const f32x4*)&lsRed_[(rq * 2 + 0) * 256 + pos];
    acc[1] += *(const f32x4*)&lsRed_[(rq * 2 + 1) * 256 + pos];
  }
  __syncthreads();   // scratch reusable
}

// ---------------- D-class (l1A) MMA: full k, 32 rows (rowbase split) ----------------
__device__ __forceinline__ void mmaD(
    const short* __restrict__ pAH, const short* __restrict__ pAL,
    int kloc0, int kkGlob0, const short* lsHi_, const short* lsLo_,
    f32x4 (&accH)[2], f32x4 (&accL)[2], int l15, int lq, int rhalf, int rowbase) {
  const int r0 = rowbase + rhalf * 16 + l15;
#pragma unroll 4
  for (int i = 0; i < 8; ++i) {
    const int kk = kkGlob0 + i * 32 + lq * 8;
    const int ka = kloc0 + i * 32 + lq * 8;
    const int e0 = (l15 * 1024 + kk) ^ ((l15 & 7) << 3);
    const int e1 = ((16 + l15) * 1024 + kk) ^ ((l15 & 7) << 3);
    bf16x8 bh0 = *(const bf16x8*)&lsHi_[e0];
    bf16x8 bl0 = *(const bf16x8*)&lsLo_[e0];
    bf16x8 bh1 = *(const bf16x8*)&lsHi_[e1];
    bf16x8 bl1 = *(const bf16x8*)&lsLo_[e1];
    bf16x8 ah = *(const bf16x8*)&pAH[r0 * 512 + ka];
    bf16x8 al = *(const bf16x8*)&pAL[r0 * 512 + ka];
    accH[0] = mma_bf16(ah, bh0, accH[0]);
    accH[1] = mma_bf16(ah, bh1, accH[1]);
    accL[0] = mma_bf16(al, bh0, accL[0]);
    accL[1] = mma_bf16(al, bh1, accL[1]);
    accL[0] = mma_bf16(ah, bl0, accL[0]);
    accL[1] = mma_bf16(ah, bl1, accL[1]);
  }
}
__device__ __forceinline__ void phaseD(
    const short* aLoH, const short* aLoL,
    const short* aHiH, const short* aHiL,
    const short* lsHi_, const short* lsLo_, float* lsRed_,
    f32x4 (&acc)[2], int wave, int l15, int lq, int rowbase) {
  const int khalf = wave >> 1, rhalf = wave & 1;
  f32x4 accH[2] = {}, accL[2] = {};
  const short* pAH = (khalf < 2) ? aLoH : aHiH;
  const short* pAL = (khalf < 2) ? aLoL : aHiL;
  mmaD(pAH, pAL, (khalf & 1) * 256, khalf * 256, lsHi_, lsLo_,
       accH, accL, l15, lq, rhalf, rowbase);
  acc[0] = accH[0] + accL[0];
  acc[1] = accH[1] + accL[1];
  const int pos = l15 * 16 + lq * 4;
  if (wave >= 2) {
    *(f32x4*)&lsRed_[((wave - 2) * 2 + 0) * 256 + pos] = acc[0];
    *(f32x4*)&lsRed_[((wave - 2) * 2 + 1) * 256 + pos] = acc[1];
  }
  __syncthreads();
  if (wave < 2) {
#pragma unroll
    for (int s = 0; s < 3; ++s) {
      const int slot = (wave & 1) + 2 * s;
      acc[0] += *(const f32x4*)&lsRed_[(slot * 2 + 0) * 256 + pos];
      acc[1] += *(const f32x4*)&lsRed_[(slot * 2 + 1) * 256 + pos];
    }
  }
  __syncthreads();
}

// weight staging: 32 rows x 1024 k as split bf16 hi/lo, XOR-swizzled
__device__ __forceinline__ void stage_weights(
    short* lsHi, short* lsLo, const float* srcBase0, const float* srcBase1,
    int jc, int tid) {
  for (int i = tid; i < 8192; i += 512) {
    const int j = i >> 8;
    const int k4 = (i & 255) << 2;
    const int g = jc + j;
    const float* src = (srcBase1 && g >= 512)
        ? (srcBase1 + (size_t)(g - 512) * 1024 + k4)
        : (srcBase0 + (size_t)g * 1024 + k4);
    f32x4 v = *(const f32x4*)src;
    s16x4 h4, l4;
#pragma unroll
    for (int q = 0; q < 4; ++q) { short hi, lo; split2(v[q], &hi, &lo); h4[q] = hi; l4[q] = lo; }
    const int els = (j * 1024 + k4) ^ ((j & 7) << 3);
    *(s16x4*)&lsHi[els] = h4;
    *(s16x4*)&lsLo[els] = l4;
  }
}

// ================= fused persistent kernel =================
__launch_bounds__(512, 1)
__global__ void k_main(
    const float* __restrict__ Wr, const float* __restrict__ Wz, const float* __restrict__ Wh,
    const float* __restrict__ Wrb, const float* __restrict__ Wzb, const float* __restrict__ Whb,
    const short* __restrict__ XeHi, const short* __restrict__ XeLo,
    short* X1Hi, short* X1Lo, _Float16* X1f16,
    short* h0Hi, short* h0Lo,
    short* rh0Hi, short* rh0Lo, short* rh1Hi, short* rh1Lo,
    float* z0, float* z1, float* hidOut,
    const _Float16* OWf, const float* outb, float* out,
    unsigned* flags) {
  __shared__ __align__(16) char pool[159744];
  short* lsHi = (short*)pool;                  // 64 KB
  short* lsLo = lsHi + 32 * 1024;              // 64 KB
  float* lsRed = (float*)(pool + 131072);      // 8 KB (P) / 12 KB (D)
  short* sH    = (short*)(pool + 131072);      // epilogue overlay (after reduce)
  short* sL    = sH + 2048;
  float* sZA   = (float*)(pool + 131072);      // A z-class out overlay
  float* sZ    = (float*)(pool + 139264);      // B: z prestage 8 KB
  short* stH   = (short*)(pool + 147456);      // B: hOld hi 4 KB
  short* stL   = stH + 2048;                   // B: hOld lo 4 KB
  _Float16* sX = (_Float16*)(pool + 155648);   // l1B X1f16 4 KB

  const int wg = blockIdx.x;
  const int tid = threadIdx.x;
  const int wave = tid >> 6, lane = tid & 63, l15 = lane & 15, lq = lane >> 4;

  // flag slots: l0A 0..31 | l1A 32..95 | l0B 96..111 | l1B 112..127
  constexpr int FA0 = 0, FA1 = 32, FB0 = 96, FB1 = 112;

  if (wg < 32) {
    // ================= l0A: gates layer 0, 32 cols, 64 rows =================
    const int cg = wg, jc = cg * 32;
    const bool isR = (jc < 512);
    stage_weights(lsHi, lsLo, Wr, Wz, jc, tid);
    float biasL0, biasL1;
    {
      const int j0 = jc + l15, j1 = j0 + 16;
      biasL0 = (j0 < 512) ? Wrb[j0] : Wzb[j0 - 512];
      biasL1 = (j1 < 512) ? Wrb[j1] : Wzb[j1 - 512];
    }
    __syncthreads();
    for (int t = 0; t < NT; ++t) {
      f32x4 accH[2] = {}, accL[2] = {};
      mmaP(XeHi + (size_t)t * SZ_H, XeLo + (size_t)t * SZ_H, 0,
           lsHi, lsLo, accH, accL, wave, l15, lq);      // static x-half (pre-wait)
      wait_flags(flags, FB0, 16, (unsigned)t);          // h0(t) ready
      const short* hH = h0Hi + (size_t)t * SZ_H;
      const short* hL = h0Lo + (size_t)t * SZ_H;
      mmaP(hH, hL, 512, lsHi, lsLo, accH, accL, wave, l15, lq);
      f32x4 acc[2];
      reduceP(lsRed, accH, accL, acc, wave, l15, lq);
      if (!(wave & 1)) {
        const int rq = wave >> 1;
#pragma unroll
        for (int ct = 0; ct < 2; ++ct) {
          const int jj = ct * 16 + l15, j = jc + jj;
          const float bv = ct ? biasL1 : biasL0;
#pragma unroll
          for (int r = 0; r < 4; ++r) {
            const int b = rq * 16 + lq * 4 + r;
            const float s = 1.0f / (1.0f + __expf(-(acc[ct][r] + bv)));
            if (isR) {
              const float hv = bf2f((unsigned short)hH[b * 512 + j]) +
                               bf2f((unsigned short)hL[b * 512 + j]);
              short hi, lo; split2(s * hv, &hi, &lo);
              sH[b * 32 + jj] = hi; sL[b * 32 + jj] = lo;
            } else {
              sZA[b * 32 + jj] = s;
            }
          }
        }
      }
      __syncthreads();
      if (isR) {
        const int buf = tid >> 8, q = tid & 255, row = q >> 2, c = q & 3;
        i32x4 v = *(const i32x4*)&(buf ? sL : sH)[row * 32 + c * 8];
        st_sc128((buf ? rh0Lo : rh0Hi) + (size_t)t * SZ_H + row * 512 + jc + c * 8, v);
      } else {
        const int row = tid >> 3, c = tid & 7;
        i32x4 v = *(const i32x4*)&sZA[row * 32 + c * 4];
        st_sc128(z0 + (size_t)t * SZ_H + row * 512 + (jc - 512) + c * 4, v);
      }
      publish(flags, FA0 + cg, (unsigned)(t + 1));
    }
  } else if (wg < 96) {
    // ================= l1A: gates layer 1, 32 cols, 32 rows (row-split) =====
    const int idx = wg - 32, cg = idx >> 1, rowbase = (idx & 1) * 32, jc = cg * 32;
    const bool isR = (jc < 512);
    stage_weights(lsHi, lsLo, Wr + (size_t)512 * 1024, Wz + (size_t)512 * 1024, jc, tid);
    float biasL0, biasL1;
    {
      const int j0 = jc + l15, j1 = j0 + 16;
      biasL0 = (j0 < 512) ? Wrb[512 + j0] : Wzb[512 + j0 - 512];
      biasL1 = (j1 < 512) ? Wrb[512 + j1] : Wzb[512 + j1 - 512];
    }
    __syncthreads();
    for (int t = 0; t < NT; ++t) {
      // wait: x1(t)=h0(t+1) needs FB0>=t+1 ; h1(t) needs FB1>=t
      if (tid < 16) {
        const unsigned* fp = &flags[(size_t)(FB0 + tid) * 32];
        while (ld_sc32u(fp) < (unsigned)(t + 1)) __builtin_amdgcn_s_sleep(1);
      } else if (tid < 32) {
        const unsigned* fp = &flags[(size_t)(FB1 + tid - 16) * 32];
        while (ld_sc32u(fp) < (unsigned)t) __builtin_amdgcn_s_sleep(1);
      }
      __syncthreads();
      const short* xH = h0Hi + (size_t)(t + 1) * SZ_H;
      const short* xL = h0Lo + (size_t)(t + 1) * SZ_H;
      const short* hH = X1Hi + (size_t)t * SZ_H;
      const short* hL = X1Lo + (size_t)t * SZ_H;
      f32x4 acc[2];
      phaseD(xH, xL, hH, hL, lsHi, lsLo, lsRed, acc, wave, l15, lq, rowbase);
      if (wave < 2) {
#pragma unroll
        for (int ct = 0; ct < 2; ++ct) {
          const int jj = ct * 16 + l15, j = jc + jj;
          const float bv = ct ? biasL1 : biasL0;
#pragma unroll
          for (int r = 0; r < 4; ++r) {
            const int lb = wave * 16 + lq * 4 + r;
            const int b = rowbase + lb;
            const float s = 1.0f / (1.0f + __expf(-(acc[ct][r] + bv)));
            if (isR) {
              const float hv = bf2f((unsigned short)hH[b * 512 + j]) +
                               bf2f((unsigned short)hL[b * 512 + j]);
              short hi, lo; split2(s * hv, &hi, &lo);
              sH[lb * 32 + jj] = hi; sL[lb * 32 + jj] = lo;
            } else {
              sZA[lb * 32 + jj] = s;
            }
          }
        }
      }
      __syncthreads();
      if (isR) {
        if (tid < 256) {
          const int buf = tid >> 7, q = tid & 127, row = q >> 2, c = q & 3;
          i32x4 v = *(const i32x4*)&(buf ? sL : sH)[row * 32 + c * 8];
          st_sc128((buf ? rh1Lo : rh1Hi) + (size_t)t * SZ_H +
                   (size_t)(rowbase + row) * 512 + jc + c * 8, v);
        }
      } else {
        if (tid < 256) {
          const int row = tid >> 3, c = tid & 7;
          i32x4 v = *(const i32x4*)&sZA[row * 32 + c * 4];
          st_sc128(z1 + (size_t)t * SZ_H + (size_t)(rowbase + row) * 512 +
                   (jc - 512) + c * 4, v);
        }
      }
      publish(flags, FA1 + idx, (unsigned)(t + 1));
    }
  } else if (wg < NWG_R) {
    // ================= B classes: candidate + state, 32 cols, 64 rows =======
    const bool isL1 = (wg >= 112);
    const int cg = isL1 ? (wg - 112) : (wg - 96);
    const int jc = cg * 32;
    const int layer = isL1 ? 1 : 0;
    stage_weights(lsHi, lsLo, Wh + (size_t)layer * 512 * 1024, nullptr, jc, tid);
    float biasL0 = Whb[layer * 512 + jc + l15];
    float biasL1 = Whb[layer * 512 + jc + 16 + l15];
    __syncthreads();
    short* myHi = isL1 ? X1Hi : h0Hi;       // own state arrays (t-indexed)
    short* myLo = isL1 ? X1Lo : h0Lo;
    const short* rhHi_ = isL1 ? rh1Hi : rh0Hi;
    const short* rhLo_ = isL1 ? rh1Lo : rh0Lo;
    const float* zArr = isL1 ? z1 : z0;
    for (int t = 0; t < NT; ++t) {
      if (isL1) wait_flags(flags, FB0, 16, (unsigned)(t + 1));   // x1(t) ready
      // prestage hOld (own cols, self-produced)
      {
        const int buf = tid >> 8, q = tid & 255, row = q >> 2, c = q & 3;
        const short* src = (buf ? myLo : myHi) + (size_t)t * SZ_H + row * 512 + jc + c * 8;
        *(i32x4*)&(buf ? stL : stH)[row * 32 + c * 8] = *(const i32x4*)src;
      }
      // precompute x-half
      f32x4 accH[2] = {}, accL[2] = {};
      if (isL1) {
        mmaP(h0Hi + (size_t)(t + 1) * SZ_H, h0Lo + (size_t)(t + 1) * SZ_H, 0,
             lsHi, lsLo, accH, accL, wave, l15, lq);
      } else {
        mmaP(XeHi + (size_t)t * SZ_H, XeLo + (size_t)t * SZ_H, 0,
             lsHi, lsLo, accH, accL, wave, l15, lq);
      }
      // wait gates
      if (isL1) wait_flags(flags, FA1, 64, (unsigned)(t + 1));
      else      wait_flags(flags, FA0, 32, (unsigned)(t + 1));
      // stage z (own cols)
      {
        const int row = tid >> 3, c = tid & 7;
        *(f32x4*)&sZ[row * 32 + c * 4] =
            *(const f32x4*)(zArr + (size_t)t * SZ_H + row * 512 + jc + c * 4);
      }
      // dependent rh-half
      mmaP(rhHi_ + (size_t)t * SZ_H, rhLo_ + (size_t)t * SZ_H, 512,
           lsHi, lsLo, accH, accL, wave, l15, lq);
      f32x4 acc[2];
      reduceP(lsRed, accH, accL, acc, wave, l15, lq);
      if (!(wave & 1)) {
        const int rq = wave >> 1;
#pragma unroll
        for (int ct = 0; ct < 2; ++ct) {
          const int jj = ct * 16 + l15, j = jc + jj;
          const float bv = ct ? biasL1 : biasL0;
#pragma unroll
          for (int r = 0; r < 4; ++r) {
            const int b = rq * 16 + lq * 4 + r;
            const float hh = tanhf(acc[ct][r] + bv);
            const float z = sZ[b * 32 + jj];
            const float ho = bf2f((unsigned short)stH[b * 32 + jj]) +
                             bf2f((unsigned short)stL[b * 32 + jj]);
            const float hn = (1.0f - z) * ho + z * hh;
            short hi, lo; split2(hn, &hi, &lo);
            sH[b * 32 + jj] = hi; sL[b * 32 + jj] = lo;
            if (isL1) sX[b * 32 + jj] = (_Float16)hn;
            if (t == NT - 1) hidOut[(size_t)layer * SZ_H + b * 512 + j] = hn;
          }
        }
      }
      __syncthreads();
      {
        const int buf = tid >> 8, q = tid & 255, row = q >> 2, c = q & 3;
        i32x4 v = *(const i32x4*)&(buf ? sL : sH)[row * 32 + c * 8];
        st_sc128((buf ? myLo : myHi) + (size_t)(t + 1) * SZ_H + row * 512 + jc + c * 8, v);
      }
      if (isL1 && tid < 256) {
        const int row = tid >> 2, c = tid & 3;
        i32x4 v = *(const i32x4*)&sX[row * 32 + c * 8];
        st_sc128(X1f16 + (size_t)t * SZ_H + row * 512 + jc + c * 8, v);
      }
      publish(flags, (isL1 ? FB1 : FB0) + cg, (unsigned)(t + 1));
    }
  } else {
    // ================= GEMM role: C[4096,32000] = X1f16 @ OWf^T + bias ======
    const int g = wg - NWG_R;
    _Float16* lsA = (_Float16*)pool;
    _Float16* lsB = lsA + 128 * 64;
    const int wr = (wave >> 2) * 64, wc = (wave & 3) * 32;
    unsigned lastR = 0;
    for (int tau = g; tau < NTILE; tau += NWG_G) {
      const int bm = tau / 250, bn = tau - bm * 250;
      const unsigned Rneed = 2u * (unsigned)bm + 2u;   // X1f16 rows t=2bm,2bm+1
      if (lastR < Rneed) {
        if (tid < 16) {
          const unsigned* fp = &flags[(size_t)(112 + tid) * 32];
          while (ld_sc32u(fp) < Rneed) __builtin_amdgcn_s_sleep(8);
        }
        lastR = Rneed;
      }
      __syncthreads();
      f32x4 acc[4][2] = {};
      const size_t arow0 = (size_t)bm * 128;
      const size_t brow0 = (size_t)bn * 128;
      for (int kb = 0; kb < 512; kb += 64) {
#pragma unroll
        for (int i = 0; i < 2; ++i) {
          int c = tid + i * 512;
          int row = c >> 3, kc = (c & 7) * 8;
          f16x8 va = *(const f16x8*)(X1f16 + (arow0 + row) * 512 + kb + kc);
          f16x8 vb = *(const f16x8*)(OWf + (brow0 + row) * 512 + kb + kc);
          int el = (row * 64 + kc) ^ ((row & 7) << 3);
          *(f16x8*)&lsA[el] = va;
          *(f16x8*)&lsB[el] = vb;
        }
        __syncthreads();
#pragma unroll
        for (int k0 = 0; k0 < 64; k0 += 32) {
          const int kk = k0 + lq * 8;
          f16x8 af[4], bfr[2];
#pragma unroll
          for (int i = 0; i < 4; ++i) {
            int ra = wr + i * 16 + l15;
            af[i] = *(const f16x8*)&lsA[(ra * 64 + kk) ^ ((ra & 7) << 3)];
          }
#pragma unroll
          for (int jt = 0; jt < 2; ++jt) {
            int rb = wc + jt * 16 + l15;
            bfr[jt] = *(const f16x8*)&lsB[(rb * 64 + kk) ^ ((rb & 7) << 3)];
          }
#pragma unroll
          for (int i = 0; i < 4; ++i)
#pragma unroll
            for (int jt = 0; jt < 2; ++jt)
              acc[i][jt] = mma_f16(af[i], bfr[jt], acc[i][jt]);
        }
        __syncthreads();
      }
#pragma unroll
      for (int i = 0; i < 4; ++i) {
#pragma unroll
        for (int jt = 0; jt < 2; ++jt) {
          const size_t col = brow0 + wc + jt * 16 + l15;
          const float bval = outb[col];
#pragma unroll
          for (int r = 0; r < 4; ++r) {
            const size_t row = arow0 + wr + i * 16 + lq * 4 + r;
            out[row * (size_t)NV + col] = acc[i][jt][r] + bval;
          }
        }
      }
    }
  }
}

// ---------------- launcher ----------------
extern "C" void kernel_launch(void* const* d_in, const int* in_sizes, int n_in,
                              void* d_out, int out_size, void* d_ws, size_t ws_size,
                              hipStream_t stream) {
  (void)in_sizes; (void)n_in; (void)out_size; (void)ws_size;
  const int*   toks = (const int*)d_in[0];
  const float* hid  = (const float*)d_in[1];
  const float* emb  = (const float*)d_in[2];
  const float* Wr   = (const float*)d_in[3];
  const float* Wrb  = (const float*)d_in[4];
  const float* Wz   = (const float*)d_in[5];
  const float* Wzb  = (const float*)d_in[6];
  const float* Wh   = (const float*)d_in[7];
  const float* Whb  = (const float*)d_in[8];
  const float* outw = (const float*)d_in[9];
  const float* outb = (const float*)d_in[10];
  float* out = (float*)d_out;

  char* base = (char*)d_ws;
  size_t off = 0;
  auto carve = [&](size_t bytes) -> char* {
    char* r = base + off;
    off = (off + bytes + 255) & ~(size_t)255;
    return r;
  };
  _Float16* OWf   = (_Float16*)carve(SZ_OW * 2);
  short*    XeHi  = (short*)carve(SZ_XE * 2);
  short*    XeLo  = (short*)carve(SZ_XE * 2);
  short*    X1Hi  = (short*)carve((size_t)(NT + 1) * SZ_H * 2);
  short*    X1Lo  = (short*)carve((size_t)(NT + 1) * SZ_H * 2);
  _Float16* X1f16 = (_Float16*)carve((size_t)NT * SZ_H * 2);
  short*    h0Hi  = (short*)carve((size_t)(NT + 1) * SZ_H * 2);
  short*    h0Lo  = (short*)carve((size_t)(NT + 1) * SZ_H * 2);
  short*    rh0Hi = (short*)carve((size_t)NT * SZ_H * 2);
  short*    rh0Lo = (short*)carve((size_t)NT * SZ_H * 2);
  short*    rh1Hi = (short*)carve((size_t)NT * SZ_H * 2);
  short*    rh1Lo = (short*)carve((size_t)NT * SZ_H * 2);
  float*    z0    = (float*)carve((size_t)NT * SZ_H * 4);
  float*    z1    = (float*)carve((size_t)NT * SZ_H * 4);
  unsigned* flags = (unsigned*)carve(32768);

  hipMemsetAsync(flags, 0, 32768, stream);

  k_prep<<<2048, 256, 0, stream>>>(outw, toks, emb, hid,
                                   OWf, XeHi, XeLo, X1Hi, X1Lo, h0Hi, h0Lo);

  k_main<<<NWG_R + NWG_G, 512, 0, stream>>>(
      Wr, Wz, Wh, Wrb, Wzb, Whb, XeHi, XeLo,
      X1Hi, X1Lo, X1f16, h0Hi, h0Lo,
      rh0Hi, rh0Lo, rh1Hi, rh1Lo, z0, z1,
      out + LOGITS, OWf, outb, out, flags);
}

// Round 7
// 790.867 us; speedup vs baseline: 5.9858x; 1.1963x over previous
//
#include <hip/hip_runtime.h>

// ---------------- constants ----------------
constexpr int NT = 64;     // timesteps
constexpr int NB = 64;     // batch
constexpr int NV = 32000;  // vocab
constexpr int NE = 512;    // embed
constexpr int NH = 512;    // hidden
// wg classes: [0,64) l0A | [64,128) l1A | [128,160) l0B | [160,192) l1B | [192,256) gemm
constexpr int NTILE = 32 * 250;

constexpr size_t SZ_OW  = (size_t)NV * NE;
constexpr size_t SZ_XE  = (size_t)NT * NB * NE;
constexpr size_t SZ_H   = (size_t)NB * NH;
constexpr size_t LOGITS = (size_t)NT * NB * NV;

typedef float f32x4 __attribute__((ext_vector_type(4)));
typedef int   i32x4 __attribute__((ext_vector_type(4)));
typedef short bf16x8 __attribute__((ext_vector_type(8)));
typedef short s16x4 __attribute__((ext_vector_type(4)));
typedef _Float16 f16x8 __attribute__((ext_vector_type(8)));

// ---------------- helpers ----------------
__device__ __forceinline__ unsigned short f2bf(float x) {
  unsigned u = __float_as_uint(x);
  u += 0x7FFFu + ((u >> 16) & 1u);            // RNE
  return (unsigned short)(u >> 16);
}
__device__ __forceinline__ float bf2f(unsigned short s) {
  return __uint_as_float(((unsigned)s) << 16);
}
__device__ __forceinline__ void split2(float v, short* hi, short* lo) {
  unsigned short h = f2bf(v);
  *hi = (short)h;
  *lo = (short)f2bf(v - bf2f(h));
}
__device__ __forceinline__ f32x4 mma_bf16(bf16x8 a, bf16x8 b, f32x4 c) {
  return __builtin_amdgcn_mfma_f32_16x16x32_bf16(a, b, c, 0, 0, 0);
}
__device__ __forceinline__ f32x4 mma_f16(f16x8 a, f16x8 b, f32x4 c) {
  return __builtin_amdgcn_mfma_f32_16x16x32_f16(a, b, c, 0, 0, 0);
}

// write-through-to-LLC stores (LLC/MALL = chip-level coherence point)
__device__ __forceinline__ void st_sc32u(unsigned* p, unsigned v) {
  asm volatile("global_store_dword %0, %1, off sc0 sc1" :: "v"(p), "v"(v) : "memory");
}
__device__ __forceinline__ void st_sc128(void* p, i32x4 v) {
  asm volatile("global_store_dwordx4 %0, %1, off sc0 sc1" :: "v"(p), "v"(v) : "memory");
}
// non-temporal store: keep the huge logits stream from thrashing the MALL
__device__ __forceinline__ void st_nt(float* p, float v) {
  asm volatile("global_store_dword %0, %1, off nt" :: "v"(p), "v"(v) : "memory");
}
// fresh MALL read, NON-atomic
__device__ __forceinline__ unsigned ld_sc32u(const unsigned* p) {
  unsigned v;
  asm volatile("global_load_dword %0, %1, off sc0 sc1\n\ts_waitcnt vmcnt(0)"
               : "=v"(v) : "v"(p) : "memory");
  return v;
}

// Publish own flag after draining this wg's data stores.
__device__ __forceinline__ void publish(unsigned* flags, int slot, unsigned val) {
  asm volatile("s_waitcnt vmcnt(0)" ::: "memory");
  __syncthreads();
  if (threadIdx.x == 0) st_sc32u(&flags[(size_t)slot * 32], val);
}

// ---------------- prep ----------------
__global__ void k_prep(
    const float* __restrict__ outw, const int* __restrict__ toks,
    const float* __restrict__ emb, const float* __restrict__ hid,
    _Float16* OWf, short* XeHi, short* XeLo,
    short* X1Hi, short* X1Lo, short* h0Hi, short* h0Lo) {
  const size_t stride = (size_t)gridDim.x * blockDim.x;
  const size_t N1 = SZ_OW, N2 = N1 + SZ_XE, N3 = N2 + SZ_H, N4 = N3 + SZ_H;
  for (size_t x = (size_t)blockIdx.x * blockDim.x + threadIdx.x; x < N4; x += stride) {
    if (x < N1) {
      OWf[x] = (_Float16)outw[x];
    } else if (x < N2) {
      size_t p = x - N1;
      size_t r = p >> 9, c = p & 511u;
      int tok = toks[r];
      float v = emb[(size_t)tok * 512 + c];
      short hi, lo; split2(v, &hi, &lo);
      XeHi[p] = hi; XeLo[p] = lo;
    } else if (x < N3) {
      size_t p = x - N2;
      short hi, lo; split2(hid[p], &hi, &lo);
      h0Hi[p] = hi; h0Lo[p] = lo;
    } else {
      size_t p = x - N3;
      short hi, lo; split2(hid[SZ_H + p], &hi, &lo);
      X1Hi[p] = hi; X1Lo[p] = lo;
    }
  }
}

// ---------------- 32-row P-class MMA: one 512-k half, 4-way k-split ----------------
// wave = kq(0..3)*2 + rhalf(0..1); activation ptrs pre-offset by rowbase*512.
__device__ __forceinline__ void mmaP32(
    const short* __restrict__ aH, const short* __restrict__ aL, int base,
    const short* lsHi_, const short* lsLo_,
    f32x4 (&accH)[2], f32x4 (&accL)[2], int wave, int l15, int lq) {
  const int kq = wave >> 1, rhalf = wave & 1;
  const int r0 = rhalf * 16 + l15;
#pragma unroll
  for (int i = 0; i < 4; ++i) {
    const int ko = kq * 128 + i * 32 + lq * 8;
    const int kg = base + ko;
    const int e0 = (l15 * 1024 + kg) ^ ((l15 & 7) << 3);
    const int e1 = ((16 + l15) * 1024 + kg) ^ ((l15 & 7) << 3);
    bf16x8 bh0 = *(const bf16x8*)&lsHi_[e0];
    bf16x8 bl0 = *(const bf16x8*)&lsLo_[e0];
    bf16x8 bh1 = *(const bf16x8*)&lsHi_[e1];
    bf16x8 bl1 = *(const bf16x8*)&lsLo_[e1];
    bf16x8 ah = *(const bf16x8*)&aH[r0 * 512 + ko];
    bf16x8 al = *(const bf16x8*)&aL[r0 * 512 + ko];
    accH[0] = mma_bf16(ah, bh0, accH[0]);
    accH[1] = mma_bf16(ah, bh1, accH[1]);
    accL[0] = mma_bf16(al, bh0, accL[0]);
    accL[1] = mma_bf16(al, bh1, accL[1]);
    accL[0] = mma_bf16(ah, bl0, accL[0]);
    accL[1] = mma_bf16(ah, bl1, accL[1]);
  }
}
// 4-way cross-wave k-reduce; owners = waves 0,1 (kq=0, rhalf=wave).
__device__ __forceinline__ void reduce4(float* lsRed_, f32x4 (&accH)[2], f32x4 (&accL)[2],
                                        f32x4 (&acc)[2], int wave, int l15, int lq) {
  const int kq = wave >> 1, rhalf = wave & 1;
  acc[0] = accH[0] + accL[0];
  acc[1] = accH[1] + accL[1];
  const int pos = l15 * 16 + lq * 4;
  if (kq) {
    *(f32x4*)&lsRed_[(((kq - 1) * 2 + rhalf) * 2 + 0) * 256 + pos] = acc[0];
    *(f32x4*)&lsRed_[(((kq - 1) * 2 + rhalf) * 2 + 1) * 256 + pos] = acc[1];
  }
  __syncthreads();
  if (!kq) {
#pragma unroll
    for (int s = 0; s < 3; ++s) {
      acc[0] += *(const f32x4*)&lsRed_[((s * 2 + rhalf) * 2 + 0) * 256 + pos];
      acc[1] += *(const f32x4*)&lsRed_[((s * 2 + rhalf) * 2 + 1) * 256 + pos];
    }
  }
  __syncthreads();
}

// ---------------- l1A full-k MMA (32 rows), as in r6 ----------------
__device__ __forceinline__ void mmaD(
    const short* __restrict__ pAH, const short* __restrict__ pAL,
    int kloc0, int kkGlob0, const short* lsHi_, const short* lsLo_,
    f32x4 (&accH)[2], f32x4 (&accL)[2], int l15, int lq, int rhalf, int rowbase) {
  const int r0 = rowbase + rhalf * 16 + l15;
#pragma unroll 4
  for (int i = 0; i < 8; ++i) {
    const int kk = kkGlob0 + i * 32 + lq * 8;
    const int ka = kloc0 + i * 32 + lq * 8;
    const int e0 = (l15 * 1024 + kk) ^ ((l15 & 7) << 3);
    const int e1 = ((16 + l15) * 1024 + kk) ^ ((l15 & 7) << 3);
    bf16x8 bh0 = *(const bf16x8*)&lsHi_[e0];
    bf16x8 bl0 = *(const bf16x8*)&lsLo_[e0];
    bf16x8 bh1 = *(const bf16x8*)&lsHi_[e1];
    bf16x8 bl1 = *(const bf16x8*)&lsLo_[e1];
    bf16x8 ah = *(const bf16x8*)&pAH[r0 * 512 + ka];
    bf16x8 al = *(const bf16x8*)&pAL[r0 * 512 + ka];
    accH[0] = mma_bf16(ah, bh0, accH[0]);
    accH[1] = mma_bf16(ah, bh1, accH[1]);
    accL[0] = mma_bf16(al, bh0, accL[0]);
    accL[1] = mma_bf16(al, bh1, accL[1]);
    accL[0] = mma_bf16(ah, bl0, accL[0]);
    accL[1] = mma_bf16(ah, bl1, accL[1]);
  }
}
__device__ __forceinline__ void phaseD(
    const short* aLoH, const short* aLoL,
    const short* aHiH, const short* aHiL,
    const short* lsHi_, const short* lsLo_, float* lsRed_,
    f32x4 (&acc)[2], int wave, int l15, int lq, int rowbase) {
  const int khalf = wave >> 1, rhalf = wave & 1;
  f32x4 accH[2] = {}, accL[2] = {};
  const short* pAH = (khalf < 2) ? aLoH : aHiH;
  const short* pAL = (khalf < 2) ? aLoL : aHiL;
  mmaD(pAH, pAL, (khalf & 1) * 256, khalf * 256, lsHi_, lsLo_,
       accH, accL, l15, lq, rhalf, rowbase);
  acc[0] = accH[0] + accL[0];
  acc[1] = accH[1] + accL[1];
  const int pos = l15 * 16 + lq * 4;
  if (wave >= 2) {
    *(f32x4*)&lsRed_[((wave - 2) * 2 + 0) * 256 + pos] = acc[0];
    *(f32x4*)&lsRed_[((wave - 2) * 2 + 1) * 256 + pos] = acc[1];
  }
  __syncthreads();
  if (wave < 2) {
#pragma unroll
    for (int s = 0; s < 3; ++s) {
      const int slot = (wave & 1) + 2 * s;
      acc[0] += *(const f32x4*)&lsRed_[(slot * 2 + 0) * 256 + pos];
      acc[1] += *(const f32x4*)&lsRed_[(slot * 2 + 1) * 256 + pos];
    }
  }
  __syncthreads();
}

// weight staging: 32 rows x 1024 k as split bf16 hi/lo, XOR-swizzled
__device__ __forceinline__ void stage_weights(
    short* lsHi, short* lsLo, const float* srcBase0, const float* srcBase1,
    int jc, int tid) {
  for (int i = tid; i < 8192; i += 512) {
    const int j = i >> 8;
    const int k4 = (i & 255) << 2;
    const int g = jc + j;
    const float* src = (srcBase1 && g >= 512)
        ? (srcBase1 + (size_t)(g - 512) * 1024 + k4)
        : (srcBase0 + (size_t)g * 1024 + k4);
    f32x4 v = *(const f32x4*)src;
    s16x4 h4, l4;
#pragma unroll
    for (int q = 0; q < 4; ++q) { short hi, lo; split2(v[q], &hi, &lo); h4[q] = hi; l4[q] = lo; }
    const int els = (j * 1024 + k4) ^ ((j & 7) << 3);
    *(s16x4*)&lsHi[els] = h4;
    *(s16x4*)&lsLo[els] = l4;
  }
}

// ---------------- shared GEMM loop (work-stealing over tiles) ----------------
__device__ void gemm_loop(char* pool, int tid,
                          const _Float16* Af, const _Float16* Bw,
                          const float* bias, float* C,
                          unsigned* flags, unsigned* tcnt) {
  _Float16* lsA = (_Float16*)pool;
  _Float16* lsB = lsA + 128 * 64;
  volatile int* bc = (volatile int*)(pool + 32768);
  const int wave = tid >> 6, lane = tid & 63, l15 = lane & 15, lq = lane >> 4;
  const int wr = (wave >> 2) * 64, wc = (wave & 3) * 32;
  unsigned lastR = 0;
  __syncthreads();
  for (;;) {
    if (tid == 0)
      *bc = (int)__hip_atomic_fetch_add(tcnt, 1u, __ATOMIC_RELAXED,
                                        __HIP_MEMORY_SCOPE_AGENT);
    __syncthreads();
    const int tau = *bc;
    __syncthreads();
    if (tau >= NTILE) break;
    const int bm = tau / 250, bn = tau - bm * 250;
    const unsigned Rneed = 2u * (unsigned)bm + 2u;
    if (lastR < Rneed) {
      if (tid < 32) {   // all 32 l1B flags
        const unsigned* fp = &flags[(size_t)(160 + tid) * 32];
        while (ld_sc32u(fp) < Rneed) __builtin_amdgcn_s_sleep(8);
      }
      lastR = Rneed;
    }
    __syncthreads();
    f32x4 acc[4][2] = {};
    const size_t arow0 = (size_t)bm * 128;
    const size_t brow0 = (size_t)bn * 128;
    for (int kb = 0; kb < 512; kb += 64) {
#pragma unroll
      for (int i = 0; i < 2; ++i) {
        int c = tid + i * 512;
        int row = c >> 3, kc = (c & 7) * 8;
        f16x8 va = *(const f16x8*)(Af + (arow0 + row) * 512 + kb + kc);
        f16x8 vb = *(const f16x8*)(Bw + (brow0 + row) * 512 + kb + kc);
        int el = (row * 64 + kc) ^ ((row & 7) << 3);
        *(f16x8*)&lsA[el] = va;
        *(f16x8*)&lsB[el] = vb;
      }
      __syncthreads();
#pragma unroll
      for (int k0 = 0; k0 < 64; k0 += 32) {
        const int kk = k0 + lq * 8;
        f16x8 af[4], bfr[2];
#pragma unroll
        for (int i = 0; i < 4; ++i) {
          int ra = wr + i * 16 + l15;
          af[i] = *(const f16x8*)&lsA[(ra * 64 + kk) ^ ((ra & 7) << 3)];
        }
#pragma unroll
        for (int jt = 0; jt < 2; ++jt) {
          int rb = wc + jt * 16 + l15;
          bfr[jt] = *(const f16x8*)&lsB[(rb * 64 + kk) ^ ((rb & 7) << 3)];
        }
#pragma unroll
        for (int i = 0; i < 4; ++i)
#pragma unroll
          for (int jt = 0; jt < 2; ++jt)
            acc[i][jt] = mma_f16(af[i], bfr[jt], acc[i][jt]);
      }
      __syncthreads();
    }
#pragma unroll
    for (int i = 0; i < 4; ++i) {
#pragma unroll
      for (int jt = 0; jt < 2; ++jt) {
        const size_t col = brow0 + wc + jt * 16 + l15;
        const float bval = bias[col];
#pragma unroll
        for (int r = 0; r < 4; ++r) {
          const size_t row = arow0 + wr + i * 16 + lq * 4 + r;
          st_nt(&C[row * (size_t)NV + col], acc[i][jt][r] + bval);
        }
      }
    }
  }
}

// ================= fused persistent kernel =================
__launch_bounds__(512, 1)
__global__ void k_main(
    const float* __restrict__ Wr, const float* __restrict__ Wz, const float* __restrict__ Wh,
    const float* __restrict__ Wrb, const float* __restrict__ Wzb, const float* __restrict__ Whb,
    const short* __restrict__ XeHi, const short* __restrict__ XeLo,
    short* X1Hi, short* X1Lo, _Float16* X1f16,
    short* h0Hi, short* h0Lo,
    short* rh0Hi, short* rh0Lo, short* rh1Hi, short* rh1Lo,
    float* z0, float* z1, float* hidOut,
    const _Float16* OWf, const float* outb, float* out,
    unsigned* flags, unsigned* tcnt) {
  __shared__ __align__(16) char pool[153600];
  short* lsHi = (short*)pool;                  // 64 KB
  short* lsLo = lsHi + 32 * 1024;              // 64 KB
  float* lsRed = (float*)(pool + 131072);      // 12 KB; overlaid by sH/sL/sZA post-reduce
  short* sH    = (short*)(pool + 131072);
  short* sL    = sH + 1024;                    // 32x32 each
  float* sZA   = (float*)(pool + 131072);
  short* stH   = (short*)(pool + 143360);      // 2 KB prestage hi
  short* stL   = stH + 1024;                   // 2 KB prestage lo
  float* sZ    = (float*)(pool + 147456);      // 4 KB z prestage
  _Float16* sX = (_Float16*)(pool + 151552);   // 2 KB X1f16 stage

  const int wg = blockIdx.x;
  const int tid = threadIdx.x;
  const int wave = tid >> 6, lane = tid & 63, l15 = lane & 15, lq = lane >> 4;

  if (wg < 64) {
    // ===== l0A: layer-0 gates, 32 cols x 32 rows =====
    const int cg = wg >> 1, rh = wg & 1, jc = cg * 32, rowbase = rh * 32;
    const bool isR = (jc < 512);
    stage_weights(lsHi, lsLo, Wr, Wz, jc, tid);
    float biasL0, biasL1;
    {
      const int j0 = jc + l15, j1 = j0 + 16;
      biasL0 = (j0 < 512) ? Wrb[j0] : Wzb[j0 - 512];
      biasL1 = (j1 < 512) ? Wrb[j1] : Wzb[j1 - 512];
    }
    __syncthreads();
    for (int t = 0; t < NT; ++t) {
      f32x4 accH[2] = {}, accL[2] = {};
      mmaP32(XeHi + (size_t)t * SZ_H + rowbase * 512,
             XeLo + (size_t)t * SZ_H + rowbase * 512, 0,
             lsHi, lsLo, accH, accL, wave, l15, lq);
      if (tid < 16) {    // l0B same-rowhalf >= t
        const unsigned* fp = &flags[(size_t)(128 + tid * 2 + rh) * 32];
        while (ld_sc32u(fp) < (unsigned)t) {}
      }
      __syncthreads();
      const short* hH = h0Hi + (size_t)t * SZ_H + rowbase * 512;
      const short* hL = h0Lo + (size_t)t * SZ_H + rowbase * 512;
      if (isR && tid < 256) {   // prestage epilogue h slice (own cols)
        const int buf = tid >> 7, q = tid & 127, row = q >> 2, c = q & 3;
        *(i32x4*)&(buf ? stL : stH)[row * 32 + c * 8] =
            *(const i32x4*)((buf ? hL : hH) + row * 512 + jc + c * 8);
      }
      mmaP32(hH, hL, 512, lsHi, lsLo, accH, accL, wave, l15, lq);
      f32x4 acc[2];
      reduce4(lsRed, accH, accL, acc, wave, l15, lq);
      if (wave < 2) {
#pragma unroll
        for (int ct = 0; ct < 2; ++ct) {
          const int jj = ct * 16 + l15;
          const float bv = ct ? biasL1 : biasL0;
#pragma unroll
          for (int r = 0; r < 4; ++r) {
            const int lb = wave * 16 + lq * 4 + r;
            const float s = 1.0f / (1.0f + __expf(-(acc[ct][r] + bv)));
            if (isR) {
              const float hv = bf2f((unsigned short)stH[lb * 32 + jj]) +
                               bf2f((unsigned short)stL[lb * 32 + jj]);
              short hi, lo; split2(s * hv, &hi, &lo);
              sH[lb * 32 + jj] = hi; sL[lb * 32 + jj] = lo;
            } else {
              sZA[lb * 32 + jj] = s;
            }
          }
        }
      }
      __syncthreads();
      if (isR) {
        if (tid < 256) {
          const int buf = tid >> 7, q = tid & 127, row = q >> 2, c = q & 3;
          i32x4 v = *(const i32x4*)&(buf ? sL : sH)[row * 32 + c * 8];
          st_sc128((buf ? rh0Lo : rh0Hi) + (size_t)t * SZ_H +
                   (size_t)(rowbase + row) * 512 + jc + c * 8, v);
        }
      } else {
        if (tid < 256) {
          const int row = tid >> 3, c = tid & 7;
          i32x4 v = *(const i32x4*)&sZA[row * 32 + c * 4];
          st_sc128(z0 + (size_t)t * SZ_H + (size_t)(rowbase + row) * 512 +
                   (jc - 512) + c * 4, v);
        }
      }
      publish(flags, wg, (unsigned)(t + 1));
    }
  } else if (wg < 128) {
    // ===== l1A: layer-1 gates, 32 cols x 32 rows, full-k =====
    const int idx = wg - 64, cg = idx >> 1, rh = idx & 1, jc = cg * 32, rowbase = rh * 32;
    const bool isR = (jc < 512);
    stage_weights(lsHi, lsLo, Wr + (size_t)512 * 1024, Wz + (size_t)512 * 1024, jc, tid);
    float biasL0, biasL1;
    {
      const int j0 = jc + l15, j1 = j0 + 16;
      biasL0 = (j0 < 512) ? Wrb[512 + j0] : Wzb[512 + j0 - 512];
      biasL1 = (j1 < 512) ? Wrb[512 + j1] : Wzb[512 + j1 - 512];
    }
    __syncthreads();
    for (int t = 0; t < NT; ++t) {
      if (tid < 16) {                 // l0B same-rh >= t+1  (x1(t))
        const unsigned* fp = &flags[(size_t)(128 + tid * 2 + rh) * 32];
        while (ld_sc32u(fp) < (unsigned)(t + 1)) {}
      } else if (tid >= 64 && tid < 80) {   // l1B same-rh >= t  (h1(t))
        const unsigned* fp = &flags[(size_t)(160 + (tid - 64) * 2 + rh) * 32];
        while (ld_sc32u(fp) < (unsigned)t) {}
      }
      __syncthreads();
      const short* xH = h0Hi + (size_t)(t + 1) * SZ_H;
      const short* xL = h0Lo + (size_t)(t + 1) * SZ_H;
      const short* hH = X1Hi + (size_t)t * SZ_H;
      const short* hL = X1Lo + (size_t)t * SZ_H;
      if (isR && tid < 256) {   // prestage epilogue h1 slice
        const int buf = tid >> 7, q = tid & 127, row = q >> 2, c = q & 3;
        *(i32x4*)&(buf ? stL : stH)[row * 32 + c * 8] =
            *(const i32x4*)((buf ? hL : hH) + (size_t)(rowbase + row) * 512 + jc + c * 8);
      }
      f32x4 acc[2];
      phaseD(xH, xL, hH, hL, lsHi, lsLo, lsRed, acc, wave, l15, lq, rowbase);
      if (wave < 2) {
#pragma unroll
        for (int ct = 0; ct < 2; ++ct) {
          const int jj = ct * 16 + l15;
          const float bv = ct ? biasL1 : biasL0;
#pragma unroll
          for (int r = 0; r < 4; ++r) {
            const int lb = wave * 16 + lq * 4 + r;
            const float s = 1.0f / (1.0f + __expf(-(acc[ct][r] + bv)));
            if (isR) {
              const float hv = bf2f((unsigned short)stH[lb * 32 + jj]) +
                               bf2f((unsigned short)stL[lb * 32 + jj]);
              short hi, lo; split2(s * hv, &hi, &lo);
              sH[lb * 32 + jj] = hi; sL[lb * 32 + jj] = lo;
            } else {
              sZA[lb * 32 + jj] = s;
            }
          }
        }
      }
      __syncthreads();
      if (isR) {
        if (tid < 256) {
          const int buf = tid >> 7, q = tid & 127, row = q >> 2, c = q & 3;
          i32x4 v = *(const i32x4*)&(buf ? sL : sH)[row * 32 + c * 8];
          st_sc128((buf ? rh1Lo : rh1Hi) + (size_t)t * SZ_H +
                   (size_t)(rowbase + row) * 512 + jc + c * 8, v);
        }
      } else {
        if (tid < 256) {
          const int row = tid >> 3, c = tid & 7;
          i32x4 v = *(const i32x4*)&sZA[row * 32 + c * 4];
          st_sc128(z1 + (size_t)t * SZ_H + (size_t)(rowbase + row) * 512 +
                   (jc - 512) + c * 4, v);
        }
      }
      publish(flags, wg, (unsigned)(t + 1));
    }
  } else if (wg < 192) {
    // ===== B classes: candidate + state, 32 cols x 32 rows =====
    const bool isL1 = (wg >= 160);
    const int idx = isL1 ? (wg - 160) : (wg - 128);
    const int cg = idx >> 1, rh = idx & 1, jc = cg * 32, rowbase = rh * 32;
    const int layer = isL1 ? 1 : 0;
    stage_weights(lsHi, lsLo, Wh + (size_t)layer * 512 * 1024, nullptr, jc, tid);
    const float biasL0 = Whb[layer * 512 + jc + l15];
    const float biasL1 = Whb[layer * 512 + jc + 16 + l15];
    __syncthreads();
    short* myHi = isL1 ? X1Hi : h0Hi;
    short* myLo = isL1 ? X1Lo : h0Lo;
    const short* rhHi_ = isL1 ? rh1Hi : rh0Hi;
    const short* rhLo_ = isL1 ? rh1Lo : rh0Lo;
    const float* zArr = isL1 ? z1 : z0;
    for (int t = 0; t < NT; ++t) {
      // prestage own hOld (self-produced, no wait)
      if (tid < 256) {
        const int buf = tid >> 7, q = tid & 127, row = q >> 2, c = q & 3;
        const short* src = (buf ? myLo : myHi) + (size_t)t * SZ_H +
                           (size_t)(rowbase + row) * 512 + jc + c * 8;
        *(i32x4*)&(buf ? stL : stH)[row * 32 + c * 8] = *(const i32x4*)src;
      }
      if (isL1) {
        if (tid < 16) {      // x1(t)=h0(t+1): l0B same-rh >= t+1
          const unsigned* fp = &flags[(size_t)(128 + tid * 2 + rh) * 32];
          while (ld_sc32u(fp) < (unsigned)(t + 1)) {}
        }
        __syncthreads();
      }
      f32x4 accH[2] = {}, accL[2] = {};
      if (isL1) {
        mmaP32(h0Hi + (size_t)(t + 1) * SZ_H + rowbase * 512,
               h0Lo + (size_t)(t + 1) * SZ_H + rowbase * 512, 0,
               lsHi, lsLo, accH, accL, wave, l15, lq);
      } else {
        mmaP32(XeHi + (size_t)t * SZ_H + rowbase * 512,
               XeLo + (size_t)t * SZ_H + rowbase * 512, 0,
               lsHi, lsLo, accH, accL, wave, l15, lq);
      }
      // wait gates (same-rowhalf A wgs >= t+1)
      if (tid < 32) {
        const int base = isL1 ? 64 : 0;
        const unsigned* fp = &flags[(size_t)(base + tid * 2 + rh) * 32];
        while (ld_sc32u(fp) < (unsigned)(t + 1)) {}
      }
      __syncthreads();
      // stage z (own cols/rows)
      if (tid < 256) {
        const int row = tid >> 3, c = tid & 7;
        *(f32x4*)&sZ[row * 32 + c * 4] =
            *(const f32x4*)(zArr + (size_t)t * SZ_H + (size_t)(rowbase + row) * 512 +
                            jc + c * 4);
      }
      mmaP32(rhHi_ + (size_t)t * SZ_H + rowbase * 512,
             rhLo_ + (size_t)t * SZ_H + rowbase * 512, 512,
             lsHi, lsLo, accH, accL, wave, l15, lq);
      f32x4 acc[2];
      reduce4(lsRed, accH, accL, acc, wave, l15, lq);
      if (wave < 2) {
#pragma unroll
        for (int ct = 0; ct < 2; ++ct) {
          const int jj = ct * 16 + l15, j = jc + jj;
          const float bv = ct ? biasL1 : biasL0;
#pragma unroll
          for (int r = 0; r < 4; ++r) {
            const int lb = wave * 16 + lq * 4 + r;
            const float hh = tanhf(acc[ct][r] + bv);
            const float z = sZ[lb * 32 + jj];
            const float ho = bf2f((unsigned short)stH[lb * 32 + jj]) +
                             bf2f((unsigned short)stL[lb * 32 + jj]);
            const float hn = (1.0f - z) * ho + z * hh;
            short hi, lo; split2(hn, &hi, &lo);
            sH[lb * 32 + jj] = hi; sL[lb * 32 + jj] = lo;
            if (isL1) sX[lb * 32 + jj] = (_Float16)hn;
            if (t == NT - 1)
              hidOut[(size_t)layer * SZ_H + (size_t)(rowbase + lb) * 512 + j] = hn;
          }
        }
      }
      __syncthreads();
      if (tid < 256) {
        const int buf = tid >> 7, q = tid & 127, row = q >> 2, c = q & 3;
        i32x4 v = *(const i32x4*)&(buf ? sL : sH)[row * 32 + c * 8];
        st_sc128((buf ? myLo : myHi) + (size_t)(t + 1) * SZ_H +
                 (size_t)(rowbase + row) * 512 + jc + c * 8, v);
      } else if (isL1 && tid < 384) {
        const int q = tid - 256, row = q >> 2, c = q & 3;
        i32x4 v = *(const i32x4*)&sX[row * 32 + c * 8];
        st_sc128(X1f16 + (size_t)t * SZ_H + (size_t)(rowbase + row) * 512 + jc + c * 8, v);
      }
      publish(flags, wg, (unsigned)(t + 1));
    }
  }
  // ===== everyone converges on the GEMM (dedicated wgs start immediately) =====
  {
    unsigned* tc = tcnt;
    gemm_loop(pool, tid, X1f16, OWf, outb, out, flags, tc);
  }
}

// ---------------- launcher ----------------
extern "C" void kernel_launch(void* const* d_in, const int* in_sizes, int n_in,
                              void* d_out, int out_size, void* d_ws, size_t ws_size,
                              hipStream_t stream) {
  (void)in_sizes; (void)n_in; (void)out_size; (void)ws_size;
  const int*   toks = (const int*)d_in[0];
  const float* hid  = (const float*)d_in[1];
  const float* emb  = (const float*)d_in[2];
  const float* Wr   = (const float*)d_in[3];
  const float* Wrb  = (const float*)d_in[4];
  const float* Wz   = (const float*)d_in[5];
  const float* Wzb  = (const float*)d_in[6];
  const float* Wh   = (const float*)d_in[7];
  const float* Whb  = (const float*)d_in[8];
  const float* outw = (const float*)d_in[9];
  const float* outb = (const float*)d_in[10];
  float* out = (float*)d_out;

  char* base = (char*)d_ws;
  size_t off = 0;
  auto carve = [&](size_t bytes) -> char* {
    char* r = base + off;
    off = (off + bytes + 255) & ~(size_t)255;
    return r;
  };
  _Float16* OWf   = (_Float16*)carve(SZ_OW * 2);
  short*    XeHi  = (short*)carve(SZ_XE * 2);
  short*    XeLo  = (short*)carve(SZ_XE * 2);
  short*    X1Hi  = (short*)carve((size_t)(NT + 1) * SZ_H * 2);
  short*    X1Lo  = (short*)carve((size_t)(NT + 1) * SZ_H * 2);
  _Float16* X1f16 = (_Float16*)carve((size_t)NT * SZ_H * 2);
  short*    h0Hi  = (short*)carve((size_t)(NT + 1) * SZ_H * 2);
  short*    h0Lo  = (short*)carve((size_t)(NT + 1) * SZ_H * 2);
  short*    rh0Hi = (short*)carve((size_t)NT * SZ_H * 2);
  short*    rh0Lo = (short*)carve((size_t)NT * SZ_H * 2);
  short*    rh1Hi = (short*)carve((size_t)NT * SZ_H * 2);
  short*    rh1Lo = (short*)carve((size_t)NT * SZ_H * 2);
  float*    z0    = (float*)carve((size_t)NT * SZ_H * 4);
  float*    z1    = (float*)carve((size_t)NT * SZ_H * 4);
  unsigned* flags = (unsigned*)carve(32768);   // 192 slots * 128B + tail
  unsigned* tcnt  = (unsigned*)carve(256);

  hipMemsetAsync(flags, 0, 32768, stream);
  hipMemsetAsync(tcnt, 0, 256, stream);

  k_prep<<<2048, 256, 0, stream>>>(outw, toks, emb, hid,
                                   OWf, XeHi, XeLo, X1Hi, X1Lo, h0Hi, h0Lo);

  k_main<<<256, 512, 0, stream>>>(
      Wr, Wz, Wh, Wrb, Wzb, Whb, XeHi, XeLo,
      X1Hi, X1Lo, X1f16, h0Hi, h0Lo,
      rh0Hi, rh0Lo, rh1Hi, rh1Lo, z0, z1,
      out + LOGITS, OWf, outb, out, flags, tcnt);
}